// Round 3
// baseline (615.235 us; speedup 1.0000x reference)
//
#include <hip/hip_runtime.h>
#include <hip/hip_bf16.h>

// Problem: L=4 B=4 N=2048 D=512 H=8 HD=64. Inputs/outputs FP32.
// Weights transposed+cast to bf16 once; bf16 MFMA, fp32 accumulate; fp32
// residual stream. scale = 512^-0.5 (D**-0.5 per ref).
// Round 12 (attn v8): triple-buffered K/V staging + counted non-draining
// vmcnt(4) + raw s_barrier (T3/T4). fill(kt+2) issued after barrier(kt);
// fill(kt+1) stays in flight across the barrier. Kills the per-kt
// __syncthreads vmcnt(0) drain (measured ~2/3 of attn wall was stall).
// 48.5 KB LDS -> 3 blocks/CU. Compute body identical to v7.

typedef __bf16 bf16x8 __attribute__((ext_vector_type(8)));
typedef float f32x4 __attribute__((ext_vector_type(4)));
typedef unsigned int u32x4 __attribute__((ext_vector_type(4)));
typedef unsigned int u32x2 __attribute__((ext_vector_type(2)));
typedef unsigned short u16;

__device__ __forceinline__ u16 f2b(float f) {  // RNE (values are finite)
  unsigned int u; __builtin_memcpy(&u, &f, 4);
  u += 0x7fffu + ((u >> 16) & 1u);
  return (u16)(u >> 16);
}
__device__ __forceinline__ bf16x8 ld8(const u16* p) {
  u32x4 t = *(const u32x4*)p;
  bf16x8 r; __builtin_memcpy(&r, &t, 16); return r;
}
__device__ __forceinline__ unsigned pkhi(float a, float b) {
  unsigned ua, ub; __builtin_memcpy(&ua, &a, 4); __builtin_memcpy(&ub, &b, 4);
  return __builtin_amdgcn_perm(ua, ub, 0x07060302u);
}

#define GLL(gp, lp) __builtin_amdgcn_global_load_lds( \
    (const __attribute__((address_space(1))) void*)(gp), \
    (__attribute__((address_space(3))) void*)(lp), 16, 0, 0)

__device__ __forceinline__ int swz(int r) { return (r + (r >> 2)) & 3; }

// ---------------------------------------------------------------------------
// All weight transposes in one launch. grid (16,16,24): z -> which(6) x l(4).
// out[l][n][k] = bf16(in[l][k][n]).
// ---------------------------------------------------------------------------
__global__ __launch_bounds__(256) void tr_all_k(
    const float* __restrict__ Wq, const float* __restrict__ Wk,
    const float* __restrict__ Wv, const float* __restrict__ Wo,
    const float* __restrict__ W1, const float* __restrict__ W2,
    u16* __restrict__ wtqkv, u16* __restrict__ wto,
    u16* __restrict__ wt1, u16* __restrict__ wt2) {
  __shared__ float t[32][33];
  int tx = threadIdx.x, ty = threadIdx.y;
  int z = blockIdx.z, which = z >> 2, l = z & 3;
  const float* in;
  u16* out;
  switch (which) {
    case 0: in = Wq; out = wtqkv + l * 786432; break;
    case 1: in = Wk; out = wtqkv + l * 786432 + 262144; break;
    case 2: in = Wv; out = wtqkv + l * 786432 + 524288; break;
    case 3: in = Wo; out = wto + l * 262144; break;
    case 4: in = W1; out = wt1 + l * 262144; break;
    default: in = W2; out = wt2 + l * 262144; break;
  }
  int k0 = blockIdx.y * 32, n0 = blockIdx.x * 32;
  const float* ip = in + l * 262144;
#pragma unroll
  for (int i = 0; i < 4; i++)
    t[ty + i * 8][tx] = ip[(k0 + ty + i * 8) * 512 + n0 + tx];
  __syncthreads();
#pragma unroll
  for (int i = 0; i < 4; i++)
    out[(n0 + ty + i * 8) * 512 + k0 + tx] = f2b(t[tx][ty + i * 8]);
}

// ---------------------------------------------------------------------------
// LayerNorm: one wave per token (D=512, 8 elems/lane), fp32 in, bf16 out
// ---------------------------------------------------------------------------
__global__ __launch_bounds__(256) void ln_k(const float* __restrict__ h,
                                            const float* __restrict__ gg,
                                            const float* __restrict__ bb,
                                            u16* __restrict__ y) {
  int tid = threadIdx.x, wave = tid >> 6, lane = tid & 63;
  int tok = blockIdx.x * 4 + wave;
  const float* hp = h + (size_t)tok * 512 + lane * 8;
  float x[8];
  *(float4*)&x[0] = *(const float4*)hp;
  *(float4*)&x[4] = *(const float4*)(hp + 4);
  float s = 0.f, ss = 0.f;
#pragma unroll
  for (int i = 0; i < 8; i++) { s += x[i]; ss += x[i] * x[i]; }
#pragma unroll
  for (int off = 1; off < 64; off <<= 1) {
    s += __shfl_xor(s, off, 64);
    ss += __shfl_xor(ss, off, 64);
  }
  float mean = s * (1.0f / 512.0f);
  float var = ss * (1.0f / 512.0f) - mean * mean;
  float rstd = rsqrtf(var + 1e-5f);
  u32x4 ov;
#pragma unroll
  for (int i = 0; i < 4; i++) {
    int d0 = lane * 8 + i * 2;
    float y0 = (x[i * 2]     - mean) * rstd * gg[d0]     + bb[d0];
    float y1 = (x[i * 2 + 1] - mean) * rstd * gg[d0 + 1] + bb[d0 + 1];
    ov[i] = (unsigned)f2b(y0) | ((unsigned)f2b(y1) << 16);
  }
  *(u32x4*)&y[(size_t)tok * 512 + lane * 8] = ov;
}

// ---------------------------------------------------------------------------
// GEMM2 v2: 64x128 tile, BK=32, double-buffered, 24 KB LDS -> 4 blocks/CU.
// grid (128 m, 4 n) -> XCD = m%8. RES preloads the 64x128 hin tile into
// 32 VGPRs before the main loop (latency hidden); epilogue = FMA + store.
// ---------------------------------------------------------------------------
enum { EPI_RES = 1, EPI_GELU = 2 };

template <int EPI>
__global__ __launch_bounds__(256, 4) void gemm2_k(
    const u16* __restrict__ A, const u16* __restrict__ Bt,
    const float* __restrict__ bias, u16* __restrict__ out0,
    const float* __restrict__ hin, float* __restrict__ hout,
    float* __restrict__ fout) {
  __shared__ __align__(16) u16 As[2][64 * 32];   // 2 x 4 KB
  __shared__ __align__(16) u16 Bs[2][128 * 32];  // 2 x 8 KB
  const int tid = threadIdx.x;
  const int wave = tid >> 6, lane = tid & 63;
  const int quad = lane >> 4, l16 = lane & 15;
  const int wm = wave >> 1, wn = wave & 1;
  const int m0 = blockIdx.x * 64;
  const int n0 = blockIdx.y * 128;
  const int mb = m0 + wm * 32, nb = n0 + wn * 64;

  // hin residual tile -> regs (RES only); completes during the main loop
  float hr[2][4][4];
  if constexpr (EPI == EPI_RES) {
#pragma unroll
    for (int mi = 0; mi < 2; ++mi)
#pragma unroll
      for (int ni = 0; ni < 4; ++ni) {
        int r0 = mb + mi * 16 + quad * 4, c = nb + ni * 16 + l16;
#pragma unroll
        for (int g = 0; g < 4; ++g)
          hr[mi][ni][g] = hin[(size_t)(r0 + g) * 512 + c];
      }
  }

  f32x4 acc[2][4];
#pragma unroll
  for (int i = 0; i < 2; i++)
#pragma unroll
    for (int j = 0; j < 4; j++) acc[i][j] = f32x4{0.f, 0.f, 0.f, 0.f};

  const int sA0 = wave * 64 + lane;
  // A: 64 rows x 4 chunks = 256 segs (1 round); B: 128 x 4 = 512 (2 rounds)
  const int rowA = sA0 >> 2, cgA = (sA0 & 3) ^ swz(rowA);
  const size_t agl = (size_t)(m0 + rowA) * 512 + cgA * 8;
  int rowB[2], cgB[2];
#pragma unroll
  for (int rnd = 0; rnd < 2; ++rnd) {
    int s = rnd * 256 + sA0;
    rowB[rnd] = s >> 2;
    cgB[rnd] = (s & 3) ^ swz(rowB[rnd]);
  }
  const size_t bgl0 = (size_t)(n0 + rowB[0]) * 512 + cgB[0] * 8;
  const size_t bgl1 = (size_t)(n0 + rowB[1]) * 512 + cgB[1] * 8;

  // frag bases (kt-invariant)
  int kbA[2], kbB[4];
#pragma unroll
  for (int mi = 0; mi < 2; ++mi) {
    int r = wm * 32 + mi * 16 + l16;
    kbA[mi] = r * 32 + (quad ^ swz(r)) * 8;
  }
#pragma unroll
  for (int ni = 0; ni < 4; ++ni) {
    int r = wn * 64 + ni * 16 + l16;
    kbB[ni] = r * 32 + (quad ^ swz(r)) * 8;
  }

  // prologue: stage kt=0 into buf 0
  GLL(A + agl, &As[0][(wave * 64) * 8]);
  GLL(Bt + bgl0, &Bs[0][(wave * 64) * 8]);
  GLL(Bt + bgl1, &Bs[0][(256 + wave * 64) * 8]);

#pragma unroll 2
  for (int kt = 0; kt < 16; ++kt) {
    __syncthreads();
    const u16* AsB = As[kt & 1];
    const u16* BsB = Bs[kt & 1];
    if (kt + 1 < 16) {
      u16* AsN = (u16*)As[(kt & 1) ^ 1];
      u16* BsN = (u16*)Bs[(kt & 1) ^ 1];
      const int k1 = (kt + 1) * 32;
      GLL(A + agl + k1, AsN + (wave * 64) * 8);
      GLL(Bt + bgl0 + k1, BsN + (wave * 64) * 8);
      GLL(Bt + bgl1 + k1, BsN + (256 + wave * 64) * 8);
    }

    bf16x8 af[2], bf_[4];
#pragma unroll
    for (int mi = 0; mi < 2; ++mi) af[mi] = ld8(AsB + kbA[mi]);
#pragma unroll
    for (int ni = 0; ni < 4; ++ni) bf_[ni] = ld8(BsB + kbB[ni]);
#pragma unroll
    for (int mi = 0; mi < 2; ++mi)
#pragma unroll
      for (int ni = 0; ni < 4; ++ni)
        acc[mi][ni] = __builtin_amdgcn_mfma_f32_16x16x32_bf16(
            af[mi], bf_[ni], acc[mi][ni], 0, 0, 0);
  }

  // Epilogue. C layout: row = quad*4+reg, col = l16.
#pragma unroll
  for (int mi = 0; mi < 2; ++mi) {
#pragma unroll
    for (int ni = 0; ni < 4; ++ni) {
      f32x4 a = acc[mi][ni];
      int r0 = mb + mi * 16 + quad * 4;
      int c = nb + ni * 16 + l16;
      float bi = bias[c];
      if constexpr (EPI == EPI_RES) {
#pragma unroll
        for (int g = 0; g < 4; ++g) {
          float v = hr[mi][ni][g] + a[g] + bi;
          hout[(size_t)(r0 + g) * 512 + c] = v;
          if (fout) fout[(size_t)(r0 + g) * 512 + c] = v;
        }
      } else {  // GELU
#pragma unroll
        for (int g = 0; g < 4; ++g) {
          float t = a[g] + bi;
          float gl = 0.5f * t * (1.0f + erff(t * 0.70710678118654752f));
          out0[(size_t)(r0 + g) * 512 + c] = f2b(gl);
        }
      }
    }
  }
}

// ---------------------------------------------------------------------------
// QKV GEMM 128x128 (BK=32), double-buffered: C[8192][1536] = A * Wqkv^T.
// grid (64 m, 12 n) -> XCD = m%8 (A-panel pinned per XCD). 32 KB LDS,
// 4 blocks/CU. One barrier per kt; next tile's GLL in flight during MFMA.
// Epilogue splits Q (pre-scaled by 512^-0.5*log2e), K, V^T.
// ---------------------------------------------------------------------------
__global__ __launch_bounds__(256, 4) void gemm_qkv_k(
    const u16* __restrict__ A, const u16* __restrict__ Bt,
    u16* __restrict__ outq, u16* __restrict__ outk, u16* __restrict__ outvt) {
  __shared__ __align__(16) u16 As[2][128 * 32];  // 2 x 8 KB
  __shared__ __align__(16) u16 Bs[2][128 * 32];  // 2 x 8 KB
  const int tid = threadIdx.x;
  const int wave = tid >> 6, lane = tid & 63;
  const int quad = lane >> 4, l16 = lane & 15;
  const int wm = wave >> 1, wn = wave & 1;
  const int m0 = blockIdx.x * 128;
  const int n0 = blockIdx.y * 128;

  f32x4 acc[4][4];
#pragma unroll
  for (int i = 0; i < 4; i++)
#pragma unroll
    for (int j = 0; j < 4; j++) acc[i][j] = f32x4{0.f, 0.f, 0.f, 0.f};

  const int sA0 = wave * 64 + lane;
  size_t agl[2], bgl[2];
#pragma unroll
  for (int rnd = 0; rnd < 2; ++rnd) {
    int s = rnd * 256 + sA0;
    int row = s >> 2, cg = (s & 3) ^ swz(row);
    agl[rnd] = (size_t)(m0 + row) * 512 + cg * 8;
    bgl[rnd] = (size_t)(n0 + row) * 512 + cg * 8;
  }

  // frag bases (kt-invariant)
  int kbA[4], kbB[4];
#pragma unroll
  for (int mi = 0; mi < 4; ++mi) {
    int r = wm * 64 + mi * 16 + l16;
    kbA[mi] = r * 32 + (quad ^ swz(r)) * 8;
  }
#pragma unroll
  for (int ni = 0; ni < 4; ++ni) {
    int r = wn * 64 + ni * 16 + l16;
    kbB[ni] = r * 32 + (quad ^ swz(r)) * 8;
  }

  // prologue: stage kt=0 into buf 0
  GLL(A + agl[0], &As[0][(wave * 64) * 8]);
  GLL(A + agl[1], &As[0][(256 + wave * 64) * 8]);
  GLL(Bt + bgl[0], &Bs[0][(wave * 64) * 8]);
  GLL(Bt + bgl[1], &Bs[0][(256 + wave * 64) * 8]);

#pragma unroll 2
  for (int kt = 0; kt < 16; ++kt) {
    __syncthreads();
    const u16* AsB = As[kt & 1];
    const u16* BsB = Bs[kt & 1];
    if (kt + 1 < 16) {
      u16* AsN = (u16*)As[(kt & 1) ^ 1];
      u16* BsN = (u16*)Bs[(kt & 1) ^ 1];
      const int k1 = (kt + 1) * 32;
      GLL(A + agl[0] + k1, AsN + (wave * 64) * 8);
      GLL(A + agl[1] + k1, AsN + (256 + wave * 64) * 8);
      GLL(Bt + bgl[0] + k1, BsN + (wave * 64) * 8);
      GLL(Bt + bgl[1] + k1, BsN + (256 + wave * 64) * 8);
    }

    bf16x8 af[4], bf_[4];
#pragma unroll
    for (int mi = 0; mi < 4; ++mi) af[mi] = ld8(AsB + kbA[mi]);
#pragma unroll
    for (int ni = 0; ni < 4; ++ni) bf_[ni] = ld8(BsB + kbB[ni]);
#pragma unroll
    for (int mi = 0; mi < 4; ++mi)
#pragma unroll
      for (int ni = 0; ni < 4; ++ni)
        acc[mi][ni] = __builtin_amdgcn_mfma_f32_16x16x32_bf16(
            af[mi], bf_[ni], acc[mi][ni], 0, 0, 0);
  }

  const int mb = m0 + wm * 64, nb = n0 + wn * 64;
#pragma unroll
  for (int mi = 0; mi < 4; ++mi) {
#pragma unroll
    for (int ni = 0; ni < 4; ++ni) {
      f32x4 a = acc[mi][ni];
      int r0 = mb + mi * 16 + quad * 4;
      int c = nb + ni * 16 + l16;
      if (c < 512) {
        const float C2 = 0.06375871506958306f;  // 512^-0.5 * log2(e)
#pragma unroll
        for (int g = 0; g < 4; ++g) outq[(size_t)(r0 + g) * 512 + c] = f2b(a[g] * C2);
      } else if (c < 1024) {
#pragma unroll
        for (int g = 0; g < 4; ++g) outk[(size_t)(r0 + g) * 512 + (c - 512)] = f2b(a[g]);
      } else {
        int cv = c - 1024, hh = cv >> 6, dd = cv & 63;
        int bb = r0 >> 11, nt = r0 & 2047;
        u32x2 pk;
        pk[0] = (unsigned)f2b(a[0]) | ((unsigned)f2b(a[1]) << 16);
        pk[1] = (unsigned)f2b(a[2]) | ((unsigned)f2b(a[3]) << 16);
        *(u32x2*)&outvt[((size_t)(bb * 8 + hh) * 64 + dd) * 2048 + nt] = pk;
      }
    }
  }
}

// ---------------------------------------------------------------------------
// Flash attention v8 (2x2 split). grid (32 bh, 32 qt) -> XCD = bh%8.
// Triple-buffered K/V (3 x 8 KB each), raw s_barrier + counted vmcnt:
//   kt: wait vmcnt(4)  [fill(kt) landed; fill(kt+1)'s 4 GLLs stay in flight]
//       s_barrier
//       issue fill(kt+2)  [safe: its buffer's readers finished at kt-1]
//       compute(kt)
// No vmcnt(0) drain in the main loop. Compute body identical to v7:
// PV full-rate 16x16x32 with k<->kv map k=quad*8+t*4+g <-> kv=kvs*32+t*16+
// quad*4+g; denominator via ones-MFMA.
// ---------------------------------------------------------------------------
__global__ __launch_bounds__(256, 3) void attn_k(const u16* __restrict__ q,
                                                 const u16* __restrict__ k,
                                                 const u16* __restrict__ vt,
                                                 u16* __restrict__ o) {
  __shared__ __align__(16) u16 S[3 * 4096 * 2];  // K[3][4096] | V[3][4096]
  __shared__ float Lr[4][32];
  const int tid = threadIdx.x, wave = tid >> 6, lane = tid & 63;
  const int quad = lane >> 4, l16 = lane & 15;
  const int swl = l16 & 7;
  const int qh2 = wave & 1, kvs = wave >> 1;
  const int bh = blockIdx.x, b = bh >> 3, h = bh & 7;
  const int qt0 = blockIdx.y * 64;

  const u16* qpb = q + (size_t)(b * 2048 + qt0 + qh2 * 32) * 512 + h * 64;
  bf16x8 aq[2][2];
#pragma unroll
  for (int qt = 0; qt < 2; ++qt) {
    const u16* qp = qpb + (size_t)(qt * 16 + l16) * 512;
    aq[qt][0] = ld8(qp + quad * 8);
    aq[qt][1] = ld8(qp + 32 + quad * 8);
  }

  const u16* kp = k + (size_t)b * 2048 * 512 + h * 64;
  const u16* vp = vt + (size_t)bh * 64 * 2048;

  const int srow = lane >> 3, schk = lane & 7, sgc = schk ^ srow;
  const int krow0 = wave * 8 + srow;
  const size_t kgl0 = (size_t)krow0 * 512 + sgc * 8;
  const size_t kgl1 = (size_t)(krow0 + 32) * 512 + sgc * 8;
  const size_t vgl0 = (size_t)krow0 * 2048 + sgc * 8;
  const size_t vgl1 = (size_t)(krow0 + 32) * 2048 + sgc * 8;

  int kb[2][2];
#pragma unroll
  for (int t = 0; t < 2; ++t) {
    kb[t][0] = (kvs * 32 + t * 16 + l16) * 64 + ((quad)     ^ swl) * 8;
    kb[t][1] = (kvs * 32 + t * 16 + l16) * 64 + ((4 + quad) ^ swl) * 8;
  }
  // V^T fragment bases: row l16 (+dt*16), col chunks (kv units of 8):
  const int vblo = l16 * 64 + (((kvs << 2) + (quad >> 1)) ^ swl) * 8 + (quad & 1) * 4;
  const int vbhi = l16 * 64 + (((kvs << 2) + 2 + (quad >> 1)) ^ swl) * 8 + (quad & 1) * 4;

  f32x4 oacc[4][2];
#pragma unroll
  for (int i = 0; i < 4; i++)
#pragma unroll
    for (int j = 0; j < 2; j++) oacc[i][j] = f32x4{0.f, 0.f, 0.f, 0.f};
  f32x4 lsacc[2];
  lsacc[0] = f32x4{0.f, 0.f, 0.f, 0.f};
  lsacc[1] = f32x4{0.f, 0.f, 0.f, 0.f};

  // bf16 ones vector for the denominator MFMA
  u32x4 onesw;
  onesw[0] = 0x3F803F80u; onesw[1] = 0x3F803F80u;
  onesw[2] = 0x3F803F80u; onesw[3] = 0x3F803F80u;
  bf16x8 onesf; __builtin_memcpy(&onesf, &onesw, 16);

  u16* Kb = S;
  u16* Vb = S + 12288;
  const int dst0 = (wave * 8) * 64, dst1 = (32 + wave * 8) * 64;

  // prologue: fill buffers 0 and 1 (kt=0, kt=1)
  GLL(kp + kgl0, Kb + dst0);
  GLL(kp + kgl1, Kb + dst1);
  GLL(vp + vgl0, Vb + dst0);
  GLL(vp + vgl1, Vb + dst1);
  GLL(kp + 32768 + kgl0, Kb + 4096 + dst0);
  GLL(kp + 32768 + kgl1, Kb + 4096 + dst1);
  GLL(vp + 64 + vgl0, Vb + 4096 + dst0);
  GLL(vp + 64 + vgl1, Vb + 4096 + dst1);

  int ofA = 0, ofB = 4096, ofC = 8192;  // cur, next, next2 (u16 offsets)

  for (int kt = 0; kt < 32; ++kt) {
    if (kt < 31) {
      asm volatile("s_waitcnt vmcnt(4)" ::: "memory");
    } else {
      asm volatile("s_waitcnt vmcnt(0)" ::: "memory");
    }
    __builtin_amdgcn_sched_barrier(0);
    __builtin_amdgcn_s_barrier();
    __builtin_amdgcn_sched_barrier(0);

    const u16* KsB = Kb + ofA;
    const u16* VsB = Vb + ofA;
    if (kt + 2 < 32) {
      const u16* kpn = kp + (size_t)(kt + 2) * 32768;
      const u16* vpn = vp + (size_t)(kt + 2) * 64;
      GLL(kpn + kgl0, Kb + ofC + dst0);
      GLL(kpn + kgl1, Kb + ofC + dst1);
      GLL(vpn + vgl0, Vb + ofC + dst0);
      GLL(vpn + vgl1, Vb + ofC + dst1);
    }

    // ---- K fragments, then all QK MFMAs back-to-back ----
    bf16x8 kf[2][2];
#pragma unroll
    for (int t = 0; t < 2; ++t) {
      kf[t][0] = ld8(KsB + kb[t][0]);
      kf[t][1] = ld8(KsB + kb[t][1]);
    }
    f32x4 sa[2][2];
    __builtin_amdgcn_s_setprio(1);
#pragma unroll
    for (int t = 0; t < 2; ++t)
#pragma unroll
      for (int qt = 0; qt < 2; ++qt) {
        f32x4 z = f32x4{0.f, 0.f, 0.f, 0.f};
        z = __builtin_amdgcn_mfma_f32_16x16x32_bf16(kf[t][0], aq[qt][0], z, 0, 0, 0);
        z = __builtin_amdgcn_mfma_f32_16x16x32_bf16(kf[t][1], aq[qt][1], z, 0, 0, 0);
        sa[t][qt] = z;
      }
    __builtin_amdgcn_s_setprio(0);

    // ---- exp + pack into P fragments (j=0..3 <- t=0, j=4..7 <- t=1) ----
    u32x4 pw[2];
#pragma unroll
    for (int t = 0; t < 2; ++t)
#pragma unroll
      for (int qt = 0; qt < 2; ++qt) {
        float p0 = __builtin_amdgcn_exp2f(sa[t][qt][0]);
        float p1 = __builtin_amdgcn_exp2f(sa[t][qt][1]);
        float p2 = __builtin_amdgcn_exp2f(sa[t][qt][2]);
        float p3 = __builtin_amdgcn_exp2f(sa[t][qt][3]);
        pw[qt][t * 2]     = pkhi(p1, p0);
        pw[qt][t * 2 + 1] = pkhi(p3, p2);
      }
    bf16x8 pf[2];
    __builtin_memcpy(&pf[0], &pw[0], 16);
    __builtin_memcpy(&pf[1], &pw[1], 16);

    // ---- PV + denominator MFMAs ----
    __builtin_amdgcn_s_setprio(1);
#pragma unroll
    for (int dt = 0; dt < 4; ++dt) {
      u32x2 lo = *(const u32x2*)(VsB + vblo + dt * 1024);
      u32x2 hi = *(const u32x2*)(VsB + vbhi + dt * 1024);
      u32x4 w;
      w[0] = lo[0]; w[1] = lo[1]; w[2] = hi[0]; w[3] = hi[1];
      bf16x8 av; __builtin_memcpy(&av, &w, 16);
#pragma unroll
      for (int qt = 0; qt < 2; ++qt)
        oacc[dt][qt] = __builtin_amdgcn_mfma_f32_16x16x32_bf16(
            av, pf[qt], oacc[dt][qt], 0, 0, 0);
    }
#pragma unroll
    for (int qt = 0; qt < 2; ++qt)
      lsacc[qt] = __builtin_amdgcn_mfma_f32_16x16x32_bf16(
          onesf, pf[qt], lsacc[qt], 0, 0, 0);
    __builtin_amdgcn_s_setprio(0);

    int tmp = ofA; ofA = ofB; ofB = ofC; ofC = tmp;
  }

  // lsacc[qt][g] = full sum over this wave's kv half for q-row qt*16+l16
  if (quad == 0) {
#pragma unroll
    for (int qt = 0; qt < 2; ++qt) Lr[wave][qt * 16 + l16] = lsacc[qt][0];
  }
  __syncthreads();

  float* R = (float*)S;
  const int l7 = lane & 7;
  if (wave >= 2) {
    float* Rw = R + (wave - 2) * 2048;
#pragma unroll
    for (int dt = 0; dt < 4; ++dt)
#pragma unroll
      for (int qt = 0; qt < 2; ++qt) {
        int s = (dt * 2 + qt) ^ l7;
        *(f32x4*)&Rw[lane * 32 + s * 4] = oacc[dt][qt];
      }
  }
  __syncthreads();
  if (wave < 2) {
    float* Rw = R + wave * 2048;
    float inv[2];
#pragma unroll
    for (int qt = 0; qt < 2; ++qt)
      inv[qt] = 1.0f / (Lr[wave][qt * 16 + l16] + Lr[wave + 2][qt * 16 + l16]);
#pragma unroll
    for (int dt = 0; dt < 4; ++dt)
#pragma unroll
      for (int qt = 0; qt < 2; ++qt) {
        int s = (dt * 2 + qt) ^ l7;
        f32x4 v = *(f32x4*)&Rw[lane * 32 + s * 4];
        float i4 = inv[qt];
        float o0 = (oacc[dt][qt][0] + v[0]) * i4;
        float o1 = (oacc[dt][qt][1] + v[1]) * i4;
        float o2 = (oacc[dt][qt][2] + v[2]) * i4;
        float o3 = (oacc[dt][qt][3] + v[3]) * i4;
        u16* op = o + (size_t)(b * 2048 + qt0 + wave * 32 + qt * 16 + l16) * 512 +
                  h * 64 + dt * 16 + quad * 4;
        u32x2 pk;
        pk[0] = (unsigned)f2b(o0) | ((unsigned)f2b(o1) << 16);
        pk[1] = (unsigned)f2b(o2) | ((unsigned)f2b(o3) << 16);
        *(u32x2*)op = pk;
      }
  }
}

// ---------------------------------------------------------------------------
extern "C" void kernel_launch(void* const* d_in, const int* in_sizes, int n_in,
                              void* d_out, int out_size, void* d_ws,
                              size_t ws_size, hipStream_t stream) {
  const float* x   = (const float*)d_in[0];
  const float* Wq  = (const float*)d_in[1];
  const float* Wk  = (const float*)d_in[2];
  const float* Wv  = (const float*)d_in[3];
  const float* Wo  = (const float*)d_in[4];
  const float* bo  = (const float*)d_in[5];
  const float* g1  = (const float*)d_in[6];
  const float* bg1 = (const float*)d_in[7];
  const float* W1  = (const float*)d_in[8];
  const float* b1  = (const float*)d_in[9];
  const float* W2  = (const float*)d_in[10];
  const float* b2  = (const float*)d_in[11];
  const float* g2  = (const float*)d_in[12];
  const float* bg2 = (const float*)d_in[13];

  char* ws = (char*)d_ws;
  float* h    = (float*)ws;                        // 16 MB fp32 residual
  u16* yb     = (u16*)(ws + (16ll << 20));         // 8 MB LN output (bf16)
  u16* qb     = (u16*)(ws + (24ll << 20));         // 8 MB q / ffn-intermediate
  u16* kb     = (u16*)(ws + (32ll << 20));         // 8 MB k
  u16* vtb    = (u16*)(ws + (40ll << 20));         // 8 MB v transposed [b,h,d,n]
  u16* ob     = (u16*)(ws + (48ll << 20));         // 8 MB attn out
  u16* wtqkv  = (u16*)(ws + (56ll << 20));         // 6 MB [l][1536][512] bf16
  u16* wto    = (u16*)(ws + (62ll << 20));         // 2 MB
  u16* wt1    = (u16*)(ws + (64ll << 20));         // 2 MB
  u16* wt2    = (u16*)(ws + (66ll << 20));         // 2 MB  (total 68 MB)

  tr_all_k<<<dim3(16, 16, 24), dim3(32, 8), 0, stream>>>(
      Wq, Wk, Wv, Wo, W1, W2, wtqkv, wto, wt1, wt2);

  for (int l = 0; l < 4; ++l) {
    const float* hsrc = (l == 0) ? x : h;
    ln_k<<<2048, 256, 0, stream>>>(hsrc, g1 + l * 512, bg1 + l * 512, yb);
    gemm_qkv_k<<<dim3(64, 12), 256, 0, stream>>>(
        yb, wtqkv + l * 786432, qb, kb, vtb);
    attn_k<<<dim3(32, 32), 256, 0, stream>>>(qb, kb, vtb, ob);
    gemm2_k<EPI_RES><<<dim3(128, 4), 256, 0, stream>>>(
        ob, wto + l * 262144, bo + l * 512, nullptr, hsrc, h, nullptr);
    ln_k<<<2048, 256, 0, stream>>>(h, g2 + l * 512, bg2 + l * 512, yb);
    gemm2_k<EPI_GELU><<<dim3(128, 4), 256, 0, stream>>>(
        yb, wt1 + l * 262144, b1 + l * 512, qb, nullptr, nullptr, nullptr);
    gemm2_k<EPI_RES><<<dim3(128, 4), 256, 0, stream>>>(
        qb, wt2 + l * 262144, b2 + l * 512, nullptr, h, h,
        (l == 3) ? (float*)d_out : nullptr);
  }
}

// Round 4
// 599.787 us; speedup vs baseline: 1.0258x; 1.0258x over previous
//
#include <hip/hip_runtime.h>
#include <hip/hip_bf16.h>

// Problem: L=4 B=4 N=2048 D=512 H=8 HD=64. Inputs/outputs FP32.
// Weights transposed+cast to bf16 once; bf16 MFMA, fp32 accumulate; fp32
// residual stream. scale = 512^-0.5 (D**-0.5 per ref).
// Round 13 (attn v9): REVERT v8 (3-buf counted-vmcnt lost occupancy 31->21%,
// regressed 47.6->61 us). Back to v7 memory schedule (2-buf, __syncthreads,
// 4 blocks/CU) + T15 cross-iteration pipeline: PV deferred one tile.
// Per kt: QK(kt) x8 -> PV(kt-1) x10 (independent, fills MFMA-latency gap)
// -> exp(kt) on VALU while PV drains. V frags of tile kt captured in regs
// (its LDS buffer is overwritten during kt+1). pf/V rotation is static.

typedef __bf16 bf16x8 __attribute__((ext_vector_type(8)));
typedef float f32x4 __attribute__((ext_vector_type(4)));
typedef unsigned int u32x4 __attribute__((ext_vector_type(4)));
typedef unsigned int u32x2 __attribute__((ext_vector_type(2)));
typedef unsigned short u16;

__device__ __forceinline__ u16 f2b(float f) {  // RNE (values are finite)
  unsigned int u; __builtin_memcpy(&u, &f, 4);
  u += 0x7fffu + ((u >> 16) & 1u);
  return (u16)(u >> 16);
}
__device__ __forceinline__ bf16x8 ld8(const u16* p) {
  u32x4 t = *(const u32x4*)p;
  bf16x8 r; __builtin_memcpy(&r, &t, 16); return r;
}
__device__ __forceinline__ unsigned pkhi(float a, float b) {
  unsigned ua, ub; __builtin_memcpy(&ua, &a, 4); __builtin_memcpy(&ub, &b, 4);
  return __builtin_amdgcn_perm(ua, ub, 0x07060302u);
}

#define GLL(gp, lp) __builtin_amdgcn_global_load_lds( \
    (const __attribute__((address_space(1))) void*)(gp), \
    (__attribute__((address_space(3))) void*)(lp), 16, 0, 0)

__device__ __forceinline__ int swz(int r) { return (r + (r >> 2)) & 3; }

// ---------------------------------------------------------------------------
// All weight transposes in one launch. grid (16,16,24): z -> which(6) x l(4).
// out[l][n][k] = bf16(in[l][k][n]).
// ---------------------------------------------------------------------------
__global__ __launch_bounds__(256) void tr_all_k(
    const float* __restrict__ Wq, const float* __restrict__ Wk,
    const float* __restrict__ Wv, const float* __restrict__ Wo,
    const float* __restrict__ W1, const float* __restrict__ W2,
    u16* __restrict__ wtqkv, u16* __restrict__ wto,
    u16* __restrict__ wt1, u16* __restrict__ wt2) {
  __shared__ float t[32][33];
  int tx = threadIdx.x, ty = threadIdx.y;
  int z = blockIdx.z, which = z >> 2, l = z & 3;
  const float* in;
  u16* out;
  switch (which) {
    case 0: in = Wq; out = wtqkv + l * 786432; break;
    case 1: in = Wk; out = wtqkv + l * 786432 + 262144; break;
    case 2: in = Wv; out = wtqkv + l * 786432 + 524288; break;
    case 3: in = Wo; out = wto + l * 262144; break;
    case 4: in = W1; out = wt1 + l * 262144; break;
    default: in = W2; out = wt2 + l * 262144; break;
  }
  int k0 = blockIdx.y * 32, n0 = blockIdx.x * 32;
  const float* ip = in + l * 262144;
#pragma unroll
  for (int i = 0; i < 4; i++)
    t[ty + i * 8][tx] = ip[(k0 + ty + i * 8) * 512 + n0 + tx];
  __syncthreads();
#pragma unroll
  for (int i = 0; i < 4; i++)
    out[(n0 + ty + i * 8) * 512 + k0 + tx] = f2b(t[tx][ty + i * 8]);
}

// ---------------------------------------------------------------------------
// LayerNorm: one wave per token (D=512, 8 elems/lane), fp32 in, bf16 out
// ---------------------------------------------------------------------------
__global__ __launch_bounds__(256) void ln_k(const float* __restrict__ h,
                                            const float* __restrict__ gg,
                                            const float* __restrict__ bb,
                                            u16* __restrict__ y) {
  int tid = threadIdx.x, wave = tid >> 6, lane = tid & 63;
  int tok = blockIdx.x * 4 + wave;
  const float* hp = h + (size_t)tok * 512 + lane * 8;
  float x[8];
  *(float4*)&x[0] = *(const float4*)hp;
  *(float4*)&x[4] = *(const float4*)(hp + 4);
  float s = 0.f, ss = 0.f;
#pragma unroll
  for (int i = 0; i < 8; i++) { s += x[i]; ss += x[i] * x[i]; }
#pragma unroll
  for (int off = 1; off < 64; off <<= 1) {
    s += __shfl_xor(s, off, 64);
    ss += __shfl_xor(ss, off, 64);
  }
  float mean = s * (1.0f / 512.0f);
  float var = ss * (1.0f / 512.0f) - mean * mean;
  float rstd = rsqrtf(var + 1e-5f);
  u32x4 ov;
#pragma unroll
  for (int i = 0; i < 4; i++) {
    int d0 = lane * 8 + i * 2;
    float y0 = (x[i * 2]     - mean) * rstd * gg[d0]     + bb[d0];
    float y1 = (x[i * 2 + 1] - mean) * rstd * gg[d0 + 1] + bb[d0 + 1];
    ov[i] = (unsigned)f2b(y0) | ((unsigned)f2b(y1) << 16);
  }
  *(u32x4*)&y[(size_t)tok * 512 + lane * 8] = ov;
}

// ---------------------------------------------------------------------------
// GEMM2 v2: 64x128 tile, BK=32, double-buffered, 24 KB LDS -> 4 blocks/CU.
// grid (128 m, 4 n) -> XCD = m%8. RES preloads the 64x128 hin tile into
// 32 VGPRs before the main loop (latency hidden); epilogue = FMA + store.
// ---------------------------------------------------------------------------
enum { EPI_RES = 1, EPI_GELU = 2 };

template <int EPI>
__global__ __launch_bounds__(256, 4) void gemm2_k(
    const u16* __restrict__ A, const u16* __restrict__ Bt,
    const float* __restrict__ bias, u16* __restrict__ out0,
    const float* __restrict__ hin, float* __restrict__ hout,
    float* __restrict__ fout) {
  __shared__ __align__(16) u16 As[2][64 * 32];   // 2 x 4 KB
  __shared__ __align__(16) u16 Bs[2][128 * 32];  // 2 x 8 KB
  const int tid = threadIdx.x;
  const int wave = tid >> 6, lane = tid & 63;
  const int quad = lane >> 4, l16 = lane & 15;
  const int wm = wave >> 1, wn = wave & 1;
  const int m0 = blockIdx.x * 64;
  const int n0 = blockIdx.y * 128;
  const int mb = m0 + wm * 32, nb = n0 + wn * 64;

  // hin residual tile -> regs (RES only); completes during the main loop
  float hr[2][4][4];
  if constexpr (EPI == EPI_RES) {
#pragma unroll
    for (int mi = 0; mi < 2; ++mi)
#pragma unroll
      for (int ni = 0; ni < 4; ++ni) {
        int r0 = mb + mi * 16 + quad * 4, c = nb + ni * 16 + l16;
#pragma unroll
        for (int g = 0; g < 4; ++g)
          hr[mi][ni][g] = hin[(size_t)(r0 + g) * 512 + c];
      }
  }

  f32x4 acc[2][4];
#pragma unroll
  for (int i = 0; i < 2; i++)
#pragma unroll
    for (int j = 0; j < 4; j++) acc[i][j] = f32x4{0.f, 0.f, 0.f, 0.f};

  const int sA0 = wave * 64 + lane;
  // A: 64 rows x 4 chunks = 256 segs (1 round); B: 128 x 4 = 512 (2 rounds)
  const int rowA = sA0 >> 2, cgA = (sA0 & 3) ^ swz(rowA);
  const size_t agl = (size_t)(m0 + rowA) * 512 + cgA * 8;
  int rowB[2], cgB[2];
#pragma unroll
  for (int rnd = 0; rnd < 2; ++rnd) {
    int s = rnd * 256 + sA0;
    rowB[rnd] = s >> 2;
    cgB[rnd] = (s & 3) ^ swz(rowB[rnd]);
  }
  const size_t bgl0 = (size_t)(n0 + rowB[0]) * 512 + cgB[0] * 8;
  const size_t bgl1 = (size_t)(n0 + rowB[1]) * 512 + cgB[1] * 8;

  // frag bases (kt-invariant)
  int kbA[2], kbB[4];
#pragma unroll
  for (int mi = 0; mi < 2; ++mi) {
    int r = wm * 32 + mi * 16 + l16;
    kbA[mi] = r * 32 + (quad ^ swz(r)) * 8;
  }
#pragma unroll
  for (int ni = 0; ni < 4; ++ni) {
    int r = wn * 64 + ni * 16 + l16;
    kbB[ni] = r * 32 + (quad ^ swz(r)) * 8;
  }

  // prologue: stage kt=0 into buf 0
  GLL(A + agl, &As[0][(wave * 64) * 8]);
  GLL(Bt + bgl0, &Bs[0][(wave * 64) * 8]);
  GLL(Bt + bgl1, &Bs[0][(256 + wave * 64) * 8]);

#pragma unroll 2
  for (int kt = 0; kt < 16; ++kt) {
    __syncthreads();
    const u16* AsB = As[kt & 1];
    const u16* BsB = Bs[kt & 1];
    if (kt + 1 < 16) {
      u16* AsN = (u16*)As[(kt & 1) ^ 1];
      u16* BsN = (u16*)Bs[(kt & 1) ^ 1];
      const int k1 = (kt + 1) * 32;
      GLL(A + agl + k1, AsN + (wave * 64) * 8);
      GLL(Bt + bgl0 + k1, BsN + (wave * 64) * 8);
      GLL(Bt + bgl1 + k1, BsN + (256 + wave * 64) * 8);
    }

    bf16x8 af[2], bf_[4];
#pragma unroll
    for (int mi = 0; mi < 2; ++mi) af[mi] = ld8(AsB + kbA[mi]);
#pragma unroll
    for (int ni = 0; ni < 4; ++ni) bf_[ni] = ld8(BsB + kbB[ni]);
#pragma unroll
    for (int mi = 0; mi < 2; ++mi)
#pragma unroll
      for (int ni = 0; ni < 4; ++ni)
        acc[mi][ni] = __builtin_amdgcn_mfma_f32_16x16x32_bf16(
            af[mi], bf_[ni], acc[mi][ni], 0, 0, 0);
  }

  // Epilogue. C layout: row = quad*4+reg, col = l16.
#pragma unroll
  for (int mi = 0; mi < 2; ++mi) {
#pragma unroll
    for (int ni = 0; ni < 4; ++ni) {
      f32x4 a = acc[mi][ni];
      int r0 = mb + mi * 16 + quad * 4;
      int c = nb + ni * 16 + l16;
      float bi = bias[c];
      if constexpr (EPI == EPI_RES) {
#pragma unroll
        for (int g = 0; g < 4; ++g) {
          float v = hr[mi][ni][g] + a[g] + bi;
          hout[(size_t)(r0 + g) * 512 + c] = v;
          if (fout) fout[(size_t)(r0 + g) * 512 + c] = v;
        }
      } else {  // GELU
#pragma unroll
        for (int g = 0; g < 4; ++g) {
          float t = a[g] + bi;
          float gl = 0.5f * t * (1.0f + erff(t * 0.70710678118654752f));
          out0[(size_t)(r0 + g) * 512 + c] = f2b(gl);
        }
      }
    }
  }
}

// ---------------------------------------------------------------------------
// QKV GEMM 128x128 (BK=32), double-buffered: C[8192][1536] = A * Wqkv^T.
// grid (64 m, 12 n) -> XCD = m%8 (A-panel pinned per XCD). 32 KB LDS,
// 4 blocks/CU. One barrier per kt; next tile's GLL in flight during MFMA.
// Epilogue splits Q (pre-scaled by 512^-0.5*log2e), K, V^T.
// ---------------------------------------------------------------------------
__global__ __launch_bounds__(256, 4) void gemm_qkv_k(
    const u16* __restrict__ A, const u16* __restrict__ Bt,
    u16* __restrict__ outq, u16* __restrict__ outk, u16* __restrict__ outvt) {
  __shared__ __align__(16) u16 As[2][128 * 32];  // 2 x 8 KB
  __shared__ __align__(16) u16 Bs[2][128 * 32];  // 2 x 8 KB
  const int tid = threadIdx.x;
  const int wave = tid >> 6, lane = tid & 63;
  const int quad = lane >> 4, l16 = lane & 15;
  const int wm = wave >> 1, wn = wave & 1;
  const int m0 = blockIdx.x * 128;
  const int n0 = blockIdx.y * 128;

  f32x4 acc[4][4];
#pragma unroll
  for (int i = 0; i < 4; i++)
#pragma unroll
    for (int j = 0; j < 4; j++) acc[i][j] = f32x4{0.f, 0.f, 0.f, 0.f};

  const int sA0 = wave * 64 + lane;
  size_t agl[2], bgl[2];
#pragma unroll
  for (int rnd = 0; rnd < 2; ++rnd) {
    int s = rnd * 256 + sA0;
    int row = s >> 2, cg = (s & 3) ^ swz(row);
    agl[rnd] = (size_t)(m0 + row) * 512 + cg * 8;
    bgl[rnd] = (size_t)(n0 + row) * 512 + cg * 8;
  }

  // frag bases (kt-invariant)
  int kbA[4], kbB[4];
#pragma unroll
  for (int mi = 0; mi < 4; ++mi) {
    int r = wm * 64 + mi * 16 + l16;
    kbA[mi] = r * 32 + (quad ^ swz(r)) * 8;
  }
#pragma unroll
  for (int ni = 0; ni < 4; ++ni) {
    int r = wn * 64 + ni * 16 + l16;
    kbB[ni] = r * 32 + (quad ^ swz(r)) * 8;
  }

  // prologue: stage kt=0 into buf 0
  GLL(A + agl[0], &As[0][(wave * 64) * 8]);
  GLL(A + agl[1], &As[0][(256 + wave * 64) * 8]);
  GLL(Bt + bgl[0], &Bs[0][(wave * 64) * 8]);
  GLL(Bt + bgl[1], &Bs[0][(256 + wave * 64) * 8]);

#pragma unroll 2
  for (int kt = 0; kt < 16; ++kt) {
    __syncthreads();
    const u16* AsB = As[kt & 1];
    const u16* BsB = Bs[kt & 1];
    if (kt + 1 < 16) {
      u16* AsN = (u16*)As[(kt & 1) ^ 1];
      u16* BsN = (u16*)Bs[(kt & 1) ^ 1];
      const int k1 = (kt + 1) * 32;
      GLL(A + agl[0] + k1, AsN + (wave * 64) * 8);
      GLL(A + agl[1] + k1, AsN + (256 + wave * 64) * 8);
      GLL(Bt + bgl[0] + k1, BsN + (wave * 64) * 8);
      GLL(Bt + bgl[1] + k1, BsN + (256 + wave * 64) * 8);
    }

    bf16x8 af[4], bf_[4];
#pragma unroll
    for (int mi = 0; mi < 4; ++mi) af[mi] = ld8(AsB + kbA[mi]);
#pragma unroll
    for (int ni = 0; ni < 4; ++ni) bf_[ni] = ld8(BsB + kbB[ni]);
#pragma unroll
    for (int mi = 0; mi < 4; ++mi)
#pragma unroll
      for (int ni = 0; ni < 4; ++ni)
        acc[mi][ni] = __builtin_amdgcn_mfma_f32_16x16x32_bf16(
            af[mi], bf_[ni], acc[mi][ni], 0, 0, 0);
  }

  const int mb = m0 + wm * 64, nb = n0 + wn * 64;
#pragma unroll
  for (int mi = 0; mi < 4; ++mi) {
#pragma unroll
    for (int ni = 0; ni < 4; ++ni) {
      f32x4 a = acc[mi][ni];
      int r0 = mb + mi * 16 + quad * 4;
      int c = nb + ni * 16 + l16;
      if (c < 512) {
        const float C2 = 0.06375871506958306f;  // 512^-0.5 * log2(e)
#pragma unroll
        for (int g = 0; g < 4; ++g) outq[(size_t)(r0 + g) * 512 + c] = f2b(a[g] * C2);
      } else if (c < 1024) {
#pragma unroll
        for (int g = 0; g < 4; ++g) outk[(size_t)(r0 + g) * 512 + (c - 512)] = f2b(a[g]);
      } else {
        int cv = c - 1024, hh = cv >> 6, dd = cv & 63;
        int bb = r0 >> 11, nt = r0 & 2047;
        u32x2 pk;
        pk[0] = (unsigned)f2b(a[0]) | ((unsigned)f2b(a[1]) << 16);
        pk[1] = (unsigned)f2b(a[2]) | ((unsigned)f2b(a[3]) << 16);
        *(u32x2*)&outvt[((size_t)(bb * 8 + hh) * 64 + dd) * 2048 + nt] = pk;
      }
    }
  }
}

// ---------------------------------------------------------------------------
// Flash attention v9 (2x2 split). grid (32 bh, 32 qt) -> XCD = bh%8.
// v7 memory schedule (2-buf, __syncthreads, GLL prefetch after barrier)
// + T15 cross-iteration pipeline: PV of tile kt-1 runs during iteration kt,
// interleaved with QK(kt) latency and exp(kt) VALU. V frags held in regs
// across the iteration boundary (LDS buffer gets overwritten).
// k<->kv map for PV: k = quad*8 + t*4 + g <-> kv = kvs*32 + t*16 + quad*4+g.
// Denominator via ones-MFMA (also deferred).
// ---------------------------------------------------------------------------
__global__ __launch_bounds__(256, 4) void attn_k(const u16* __restrict__ q,
                                                 const u16* __restrict__ k,
                                                 const u16* __restrict__ vt,
                                                 u16* __restrict__ o) {
  __shared__ __align__(16) u16 Ks[2][64 * 64];   // 16 KB
  __shared__ __align__(16) u16 Vs[2][64 * 64];   // 16 KB
  __shared__ float Lr[4][32];                    // 512 B
  const int tid = threadIdx.x, wave = tid >> 6, lane = tid & 63;
  const int quad = lane >> 4, l16 = lane & 15;
  const int swl = l16 & 7;
  const int qh2 = wave & 1, kvs = wave >> 1;
  const int bh = blockIdx.x, b = bh >> 3, h = bh & 7;
  const int qt0 = blockIdx.y * 64;

  const u16* qpb = q + (size_t)(b * 2048 + qt0 + qh2 * 32) * 512 + h * 64;
  bf16x8 aq[2][2];
#pragma unroll
  for (int qt = 0; qt < 2; ++qt) {
    const u16* qp = qpb + (size_t)(qt * 16 + l16) * 512;
    aq[qt][0] = ld8(qp + quad * 8);
    aq[qt][1] = ld8(qp + 32 + quad * 8);
  }

  const u16* kp = k + (size_t)b * 2048 * 512 + h * 64;
  const u16* vp = vt + (size_t)bh * 64 * 2048;

  const int srow = lane >> 3, schk = lane & 7, sgc = schk ^ srow;
  const int krow0 = wave * 8 + srow;
  const size_t kgl0 = (size_t)krow0 * 512 + sgc * 8;
  const size_t kgl1 = (size_t)(krow0 + 32) * 512 + sgc * 8;
  const size_t vgl0 = (size_t)krow0 * 2048 + sgc * 8;
  const size_t vgl1 = (size_t)(krow0 + 32) * 2048 + sgc * 8;

  int kb[2][2];
#pragma unroll
  for (int t = 0; t < 2; ++t) {
    kb[t][0] = (kvs * 32 + t * 16 + l16) * 64 + ((quad)     ^ swl) * 8;
    kb[t][1] = (kvs * 32 + t * 16 + l16) * 64 + ((4 + quad) ^ swl) * 8;
  }
  // V^T fragment bases: row l16 (+dt*16), col chunks (kv units of 8):
  const int vblo = l16 * 64 + (((kvs << 2) + (quad >> 1)) ^ swl) * 8 + (quad & 1) * 4;
  const int vbhi = l16 * 64 + (((kvs << 2) + 2 + (quad >> 1)) ^ swl) * 8 + (quad & 1) * 4;

  f32x4 oacc[4][2];
#pragma unroll
  for (int i = 0; i < 4; i++)
#pragma unroll
    for (int j = 0; j < 2; j++) oacc[i][j] = f32x4{0.f, 0.f, 0.f, 0.f};
  f32x4 lsacc[2];
  lsacc[0] = f32x4{0.f, 0.f, 0.f, 0.f};
  lsacc[1] = f32x4{0.f, 0.f, 0.f, 0.f};

  // bf16 ones vector for the denominator MFMA
  u32x4 onesw;
  onesw[0] = 0x3F803F80u; onesw[1] = 0x3F803F80u;
  onesw[2] = 0x3F803F80u; onesw[3] = 0x3F803F80u;
  bf16x8 onesf; __builtin_memcpy(&onesf, &onesw, 16);

  GLL(kp + kgl0, &Ks[0][(wave * 8) * 64]);
  GLL(kp + kgl1, &Ks[0][(32 + wave * 8) * 64]);
  GLL(vp + vgl0, &Vs[0][(wave * 8) * 64]);
  GLL(vp + vgl1, &Vs[0][(32 + wave * 8) * 64]);

  // cross-iteration pipeline state (tile kt-1)
  bf16x8 pfp[2];
  bf16x8 vprev[4];

#pragma unroll 2
  for (int kt = 0; kt < 32; ++kt) {
    __syncthreads();
    const u16* KsB = Ks[kt & 1];
    const u16* VsB = Vs[kt & 1];
    if (kt + 1 < 32) {
      u16* KsN = (u16*)Ks[(kt & 1) ^ 1];
      u16* VsN = (u16*)Vs[(kt & 1) ^ 1];
      const u16* kpn = kp + (size_t)(kt + 1) * 32768;
      const u16* vpn = vp + (size_t)(kt + 1) * 64;
      GLL(kpn + kgl0, KsN + (wave * 8) * 64);
      GLL(kpn + kgl1, KsN + (32 + wave * 8) * 64);
      GLL(vpn + vgl0, VsN + (wave * 8) * 64);
      GLL(vpn + vgl1, VsN + (32 + wave * 8) * 64);
    }

    // ---- K fragments, then all QK MFMAs back-to-back ----
    bf16x8 kf[2][2];
#pragma unroll
    for (int t = 0; t < 2; ++t) {
      kf[t][0] = ld8(KsB + kb[t][0]);
      kf[t][1] = ld8(KsB + kb[t][1]);
    }
    f32x4 sa[2][2];
    __builtin_amdgcn_s_setprio(1);
#pragma unroll
    for (int t = 0; t < 2; ++t)
#pragma unroll
      for (int qt = 0; qt < 2; ++qt) {
        f32x4 z = f32x4{0.f, 0.f, 0.f, 0.f};
        z = __builtin_amdgcn_mfma_f32_16x16x32_bf16(kf[t][0], aq[qt][0], z, 0, 0, 0);
        z = __builtin_amdgcn_mfma_f32_16x16x32_bf16(kf[t][1], aq[qt][1], z, 0, 0, 0);
        sa[t][qt] = z;
      }

    // ---- PV(kt-1): independent of sa; fills the MFMA pipe while QK's
    // results are in flight, overlaps with the exp below ----
    if (kt) {
#pragma unroll
      for (int dt = 0; dt < 4; ++dt)
#pragma unroll
        for (int qt = 0; qt < 2; ++qt)
          oacc[dt][qt] = __builtin_amdgcn_mfma_f32_16x16x32_bf16(
              vprev[dt], pfp[qt], oacc[dt][qt], 0, 0, 0);
#pragma unroll
      for (int qt = 0; qt < 2; ++qt)
        lsacc[qt] = __builtin_amdgcn_mfma_f32_16x16x32_bf16(
            onesf, pfp[qt], lsacc[qt], 0, 0, 0);
    }
    __builtin_amdgcn_s_setprio(0);

    // ---- V frags of CURRENT tile -> regs (buffer dies next iteration) ----
#pragma unroll
    for (int dt = 0; dt < 4; ++dt) {
      u32x2 lo = *(const u32x2*)(VsB + vblo + dt * 1024);
      u32x2 hi = *(const u32x2*)(VsB + vbhi + dt * 1024);
      u32x4 w;
      w[0] = lo[0]; w[1] = lo[1]; w[2] = hi[0]; w[3] = hi[1];
      __builtin_memcpy(&vprev[dt], &w, 16);
    }

    // ---- exp + pack into P fragments (j=0..3 <- t=0, j=4..7 <- t=1) ----
    u32x4 pw[2];
#pragma unroll
    for (int t = 0; t < 2; ++t)
#pragma unroll
      for (int qt = 0; qt < 2; ++qt) {
        float p0 = __builtin_amdgcn_exp2f(sa[t][qt][0]);
        float p1 = __builtin_amdgcn_exp2f(sa[t][qt][1]);
        float p2 = __builtin_amdgcn_exp2f(sa[t][qt][2]);
        float p3 = __builtin_amdgcn_exp2f(sa[t][qt][3]);
        pw[qt][t * 2]     = pkhi(p1, p0);
        pw[qt][t * 2 + 1] = pkhi(p3, p2);
      }
    __builtin_memcpy(&pfp[0], &pw[0], 16);
    __builtin_memcpy(&pfp[1], &pw[1], 16);
  }

  // ---- final PV (tile 31) ----
  __builtin_amdgcn_s_setprio(1);
#pragma unroll
  for (int dt = 0; dt < 4; ++dt)
#pragma unroll
    for (int qt = 0; qt < 2; ++qt)
      oacc[dt][qt] = __builtin_amdgcn_mfma_f32_16x16x32_bf16(
          vprev[dt], pfp[qt], oacc[dt][qt], 0, 0, 0);
#pragma unroll
  for (int qt = 0; qt < 2; ++qt)
    lsacc[qt] = __builtin_amdgcn_mfma_f32_16x16x32_bf16(
        onesf, pfp[qt], lsacc[qt], 0, 0, 0);
  __builtin_amdgcn_s_setprio(0);

  // lsacc[qt][g] = full sum over this wave's kv half for q-row qt*16+l16
  if (quad == 0) {
#pragma unroll
    for (int qt = 0; qt < 2; ++qt) Lr[wave][qt * 16 + l16] = lsacc[qt][0];
  }
  __syncthreads();

  float* R = (float*)&Ks[0][0];
  const int l7 = lane & 7;
  if (wave >= 2) {
    float* Rw = R + (wave - 2) * 2048;
#pragma unroll
    for (int dt = 0; dt < 4; ++dt)
#pragma unroll
      for (int qt = 0; qt < 2; ++qt) {
        int s = (dt * 2 + qt) ^ l7;
        *(f32x4*)&Rw[lane * 32 + s * 4] = oacc[dt][qt];
      }
  }
  __syncthreads();
  if (wave < 2) {
    float* Rw = R + wave * 2048;
    float inv[2];
#pragma unroll
    for (int qt = 0; qt < 2; ++qt)
      inv[qt] = 1.0f / (Lr[wave][qt * 16 + l16] + Lr[wave + 2][qt * 16 + l16]);
#pragma unroll
    for (int dt = 0; dt < 4; ++dt)
#pragma unroll
      for (int qt = 0; qt < 2; ++qt) {
        int s = (dt * 2 + qt) ^ l7;
        f32x4 v = *(f32x4*)&Rw[lane * 32 + s * 4];
        float i4 = inv[qt];
        float o0 = (oacc[dt][qt][0] + v[0]) * i4;
        float o1 = (oacc[dt][qt][1] + v[1]) * i4;
        float o2 = (oacc[dt][qt][2] + v[2]) * i4;
        float o3 = (oacc[dt][qt][3] + v[3]) * i4;
        u16* op = o + (size_t)(b * 2048 + qt0 + wave * 32 + qt * 16 + l16) * 512 +
                  h * 64 + dt * 16 + quad * 4;
        u32x2 pk;
        pk[0] = (unsigned)f2b(o0) | ((unsigned)f2b(o1) << 16);
        pk[1] = (unsigned)f2b(o2) | ((unsigned)f2b(o3) << 16);
        *(u32x2*)op = pk;
      }
  }
}

// ---------------------------------------------------------------------------
extern "C" void kernel_launch(void* const* d_in, const int* in_sizes, int n_in,
                              void* d_out, int out_size, void* d_ws,
                              size_t ws_size, hipStream_t stream) {
  const float* x   = (const float*)d_in[0];
  const float* Wq  = (const float*)d_in[1];
  const float* Wk  = (const float*)d_in[2];
  const float* Wv  = (const float*)d_in[3];
  const float* Wo  = (const float*)d_in[4];
  const float* bo  = (const float*)d_in[5];
  const float* g1  = (const float*)d_in[6];
  const float* bg1 = (const float*)d_in[7];
  const float* W1  = (const float*)d_in[8];
  const float* b1  = (const float*)d_in[9];
  const float* W2  = (const float*)d_in[10];
  const float* b2  = (const float*)d_in[11];
  const float* g2  = (const float*)d_in[12];
  const float* bg2 = (const float*)d_in[13];

  char* ws = (char*)d_ws;
  float* h    = (float*)ws;                        // 16 MB fp32 residual
  u16* yb     = (u16*)(ws + (16ll << 20));         // 8 MB LN output (bf16)
  u16* qb     = (u16*)(ws + (24ll << 20));         // 8 MB q / ffn-intermediate
  u16* kb     = (u16*)(ws + (32ll << 20));         // 8 MB k
  u16* vtb    = (u16*)(ws + (40ll << 20));         // 8 MB v transposed [b,h,d,n]
  u16* ob     = (u16*)(ws + (48ll << 20));         // 8 MB attn out
  u16* wtqkv  = (u16*)(ws + (56ll << 20));         // 6 MB [l][1536][512] bf16
  u16* wto    = (u16*)(ws + (62ll << 20));         // 2 MB
  u16* wt1    = (u16*)(ws + (64ll << 20));         // 2 MB
  u16* wt2    = (u16*)(ws + (66ll << 20));         // 2 MB  (total 68 MB)

  tr_all_k<<<dim3(16, 16, 24), dim3(32, 8), 0, stream>>>(
      Wq, Wk, Wv, Wo, W1, W2, wtqkv, wto, wt1, wt2);

  for (int l = 0; l < 4; ++l) {
    const float* hsrc = (l == 0) ? x : h;
    ln_k<<<2048, 256, 0, stream>>>(hsrc, g1 + l * 512, bg1 + l * 512, yb);
    gemm_qkv_k<<<dim3(64, 12), 256, 0, stream>>>(
        yb, wtqkv + l * 786432, qb, kb, vtb);
    attn_k<<<dim3(32, 32), 256, 0, stream>>>(qb, kb, vtb, ob);
    gemm2_k<EPI_RES><<<dim3(128, 4), 256, 0, stream>>>(
        ob, wto + l * 262144, bo + l * 512, nullptr, hsrc, h, nullptr);
    ln_k<<<2048, 256, 0, stream>>>(h, g2 + l * 512, bg2 + l * 512, yb);
    gemm2_k<EPI_GELU><<<dim3(128, 4), 256, 0, stream>>>(
        yb, wt1 + l * 262144, b1 + l * 512, qb, nullptr, nullptr, nullptr);
    gemm2_k<EPI_RES><<<dim3(128, 4), 256, 0, stream>>>(
        qb, wt2 + l * 262144, b2 + l * 512, nullptr, h, h,
        (l == 3) ? (float*)d_out : nullptr);
  }
}

// Round 6
// 589.519 us; speedup vs baseline: 1.0436x; 1.0174x over previous
//
#include <hip/hip_runtime.h>
#include <hip/hip_bf16.h>

// Problem: L=4 B=4 N=2048 D=512 H=8 HD=64. Inputs/outputs FP32.
// Weights transposed+cast to bf16 once; bf16 MFMA, fp32 accumulate; fp32
// residual stream. scale = 512^-0.5 (D**-0.5 per ref).
// Round 15 == Round 14 resubmitted (round-5 bench was an infra failure:
// "container failed twice", no counters).
//  - attn: v7 (round-11 best, 47.6us).
//  - gemm2: 512 threads / 8 waves (2x4), same 64x128 tile + BK=32 dbuf +
//    identical LDS image. 16 waves/CU (was 8).
//  - gemm_qkv: 64x128 tile (gemm2 structure), grid (128,12) = 6 blocks/CU
//    = 24 waves/CU. launch_bounds(256,6).

typedef __bf16 bf16x8 __attribute__((ext_vector_type(8)));
typedef float f32x4 __attribute__((ext_vector_type(4)));
typedef unsigned int u32x4 __attribute__((ext_vector_type(4)));
typedef unsigned int u32x2 __attribute__((ext_vector_type(2)));
typedef unsigned short u16;

__device__ __forceinline__ u16 f2b(float f) {  // RNE (values are finite)
  unsigned int u; __builtin_memcpy(&u, &f, 4);
  u += 0x7fffu + ((u >> 16) & 1u);
  return (u16)(u >> 16);
}
__device__ __forceinline__ bf16x8 ld8(const u16* p) {
  u32x4 t = *(const u32x4*)p;
  bf16x8 r; __builtin_memcpy(&r, &t, 16); return r;
}
__device__ __forceinline__ unsigned pkhi(float a, float b) {
  unsigned ua, ub; __builtin_memcpy(&ua, &a, 4); __builtin_memcpy(&ub, &b, 4);
  return __builtin_amdgcn_perm(ua, ub, 0x07060302u);
}

#define GLL(gp, lp) __builtin_amdgcn_global_load_lds( \
    (const __attribute__((address_space(1))) void*)(gp), \
    (__attribute__((address_space(3))) void*)(lp), 16, 0, 0)

__device__ __forceinline__ int swz(int r) { return (r + (r >> 2)) & 3; }

// ---------------------------------------------------------------------------
// All weight transposes in one launch. grid (16,16,24): z -> which(6) x l(4).
// out[l][n][k] = bf16(in[l][k][n]).
// ---------------------------------------------------------------------------
__global__ __launch_bounds__(256) void tr_all_k(
    const float* __restrict__ Wq, const float* __restrict__ Wk,
    const float* __restrict__ Wv, const float* __restrict__ Wo,
    const float* __restrict__ W1, const float* __restrict__ W2,
    u16* __restrict__ wtqkv, u16* __restrict__ wto,
    u16* __restrict__ wt1, u16* __restrict__ wt2) {
  __shared__ float t[32][33];
  int tx = threadIdx.x, ty = threadIdx.y;
  int z = blockIdx.z, which = z >> 2, l = z & 3;
  const float* in;
  u16* out;
  switch (which) {
    case 0: in = Wq; out = wtqkv + l * 786432; break;
    case 1: in = Wk; out = wtqkv + l * 786432 + 262144; break;
    case 2: in = Wv; out = wtqkv + l * 786432 + 524288; break;
    case 3: in = Wo; out = wto + l * 262144; break;
    case 4: in = W1; out = wt1 + l * 262144; break;
    default: in = W2; out = wt2 + l * 262144; break;
  }
  int k0 = blockIdx.y * 32, n0 = blockIdx.x * 32;
  const float* ip = in + l * 262144;
#pragma unroll
  for (int i = 0; i < 4; i++)
    t[ty + i * 8][tx] = ip[(k0 + ty + i * 8) * 512 + n0 + tx];
  __syncthreads();
#pragma unroll
  for (int i = 0; i < 4; i++)
    out[(n0 + ty + i * 8) * 512 + k0 + tx] = f2b(t[tx][ty + i * 8]);
}

// ---------------------------------------------------------------------------
// LayerNorm: one wave per token (D=512, 8 elems/lane), fp32 in, bf16 out
// ---------------------------------------------------------------------------
__global__ __launch_bounds__(256) void ln_k(const float* __restrict__ h,
                                            const float* __restrict__ gg,
                                            const float* __restrict__ bb,
                                            u16* __restrict__ y) {
  int tid = threadIdx.x, wave = tid >> 6, lane = tid & 63;
  int tok = blockIdx.x * 4 + wave;
  const float* hp = h + (size_t)tok * 512 + lane * 8;
  float x[8];
  *(float4*)&x[0] = *(const float4*)hp;
  *(float4*)&x[4] = *(const float4*)(hp + 4);
  float s = 0.f, ss = 0.f;
#pragma unroll
  for (int i = 0; i < 8; i++) { s += x[i]; ss += x[i] * x[i]; }
#pragma unroll
  for (int off = 1; off < 64; off <<= 1) {
    s += __shfl_xor(s, off, 64);
    ss += __shfl_xor(ss, off, 64);
  }
  float mean = s * (1.0f / 512.0f);
  float var = ss * (1.0f / 512.0f) - mean * mean;
  float rstd = rsqrtf(var + 1e-5f);
  u32x4 ov;
#pragma unroll
  for (int i = 0; i < 4; i++) {
    int d0 = lane * 8 + i * 2;
    float y0 = (x[i * 2]     - mean) * rstd * gg[d0]     + bb[d0];
    float y1 = (x[i * 2 + 1] - mean) * rstd * gg[d0 + 1] + bb[d0 + 1];
    ov[i] = (unsigned)f2b(y0) | ((unsigned)f2b(y1) << 16);
  }
  *(u32x4*)&y[(size_t)tok * 512 + lane * 8] = ov;
}

// ---------------------------------------------------------------------------
// GEMM2 v3: 64x128 tile, BK=32, double-buffered, 24 KB LDS, 512 threads
// (8 waves, 2x4; wave-tile 32x32). grid (128 m, 4 n) -> 2 blocks/CU =
// 16 waves/CU. Staging: A (256 segs) by waves 0-3, B (512 segs) by all;
// LDS image identical to the 256-thread version. RES preloads hin tile.
// ---------------------------------------------------------------------------
enum { EPI_RES = 1, EPI_GELU = 2 };

template <int EPI>
__global__ __launch_bounds__(512, 4) void gemm2_k(
    const u16* __restrict__ A, const u16* __restrict__ Bt,
    const float* __restrict__ bias, u16* __restrict__ out0,
    const float* __restrict__ hin, float* __restrict__ hout,
    float* __restrict__ fout) {
  __shared__ __align__(16) u16 As[2][64 * 32];   // 2 x 4 KB
  __shared__ __align__(16) u16 Bs[2][128 * 32];  // 2 x 8 KB
  const int tid = threadIdx.x;
  const int wave = tid >> 6, lane = tid & 63;
  const int quad = lane >> 4, l16 = lane & 15;
  const int wm = wave >> 2, wn = wave & 3;
  const int m0 = blockIdx.x * 64;
  const int n0 = blockIdx.y * 128;
  const int mb = m0 + wm * 32, nb = n0 + wn * 32;

  // hin residual tile -> regs (RES only); completes during the main loop
  float hr[2][2][4];
  if constexpr (EPI == EPI_RES) {
#pragma unroll
    for (int mi = 0; mi < 2; ++mi)
#pragma unroll
      for (int ni = 0; ni < 2; ++ni) {
        int r0 = mb + mi * 16 + quad * 4, c = nb + ni * 16 + l16;
#pragma unroll
        for (int g = 0; g < 4; ++g)
          hr[mi][ni][g] = hin[(size_t)(r0 + g) * 512 + c];
      }
  }

  f32x4 acc[2][2];
#pragma unroll
  for (int i = 0; i < 2; i++)
#pragma unroll
    for (int j = 0; j < 2; j++) acc[i][j] = f32x4{0.f, 0.f, 0.f, 0.f};

  // A: 256 segs (tid<256, 1 GLL); B: 512 segs (all threads, 1 GLL)
  const int rowA = (tid & 255) >> 2, cgA = (tid & 3) ^ swz(rowA);
  const size_t agl = (size_t)(m0 + rowA) * 512 + cgA * 8;
  const int rowB = tid >> 2, cgB = (tid & 3) ^ swz(rowB);
  const size_t bgl = (size_t)(n0 + rowB) * 512 + cgB * 8;

  // frag bases (kt-invariant)
  int kbA[2], kbB[2];
#pragma unroll
  for (int mi = 0; mi < 2; ++mi) {
    int r = wm * 32 + mi * 16 + l16;
    kbA[mi] = r * 32 + (quad ^ swz(r)) * 8;
  }
#pragma unroll
  for (int ni = 0; ni < 2; ++ni) {
    int r = wn * 32 + ni * 16 + l16;
    kbB[ni] = r * 32 + (quad ^ swz(r)) * 8;
  }

  // prologue: stage kt=0 into buf 0
  if (tid < 256) GLL(A + agl, &As[0][(wave * 64) * 8]);
  GLL(Bt + bgl, &Bs[0][(wave * 64) * 8]);

#pragma unroll 2
  for (int kt = 0; kt < 16; ++kt) {
    __syncthreads();
    const u16* AsB = As[kt & 1];
    const u16* BsB = Bs[kt & 1];
    if (kt + 1 < 16) {
      u16* AsN = (u16*)As[(kt & 1) ^ 1];
      u16* BsN = (u16*)Bs[(kt & 1) ^ 1];
      const int k1 = (kt + 1) * 32;
      if (tid < 256) GLL(A + agl + k1, AsN + (wave * 64) * 8);
      GLL(Bt + bgl + k1, BsN + (wave * 64) * 8);
    }

    bf16x8 af[2], bf_[2];
#pragma unroll
    for (int mi = 0; mi < 2; ++mi) af[mi] = ld8(AsB + kbA[mi]);
#pragma unroll
    for (int ni = 0; ni < 2; ++ni) bf_[ni] = ld8(BsB + kbB[ni]);
#pragma unroll
    for (int mi = 0; mi < 2; ++mi)
#pragma unroll
      for (int ni = 0; ni < 2; ++ni)
        acc[mi][ni] = __builtin_amdgcn_mfma_f32_16x16x32_bf16(
            af[mi], bf_[ni], acc[mi][ni], 0, 0, 0);
  }

  // Epilogue. C layout: row = quad*4+reg, col = l16.
#pragma unroll
  for (int mi = 0; mi < 2; ++mi) {
#pragma unroll
    for (int ni = 0; ni < 2; ++ni) {
      f32x4 a = acc[mi][ni];
      int r0 = mb + mi * 16 + quad * 4;
      int c = nb + ni * 16 + l16;
      float bi = bias[c];
      if constexpr (EPI == EPI_RES) {
#pragma unroll
        for (int g = 0; g < 4; ++g) {
          float v = hr[mi][ni][g] + a[g] + bi;
          hout[(size_t)(r0 + g) * 512 + c] = v;
          if (fout) fout[(size_t)(r0 + g) * 512 + c] = v;
        }
      } else {  // GELU
#pragma unroll
        for (int g = 0; g < 4; ++g) {
          float t = a[g] + bi;
          float gl = 0.5f * t * (1.0f + erff(t * 0.70710678118654752f));
          out0[(size_t)(r0 + g) * 512 + c] = f2b(gl);
        }
      }
    }
  }
}

// ---------------------------------------------------------------------------
// QKV GEMM v2: 64x128 tile, BK=32, double-buffered, 24 KB LDS, 256 threads.
// grid (128 m, 12 n) -> 1536 blocks = 6 blocks/CU = 24 waves/CU.
// XCD = m%8. Epilogue splits Q (pre-scaled by 512^-0.5*log2e), K, V^T.
// ---------------------------------------------------------------------------
__global__ __launch_bounds__(256, 6) void gemm_qkv_k(
    const u16* __restrict__ A, const u16* __restrict__ Bt,
    u16* __restrict__ outq, u16* __restrict__ outk, u16* __restrict__ outvt) {
  __shared__ __align__(16) u16 As[2][64 * 32];   // 2 x 4 KB
  __shared__ __align__(16) u16 Bs[2][128 * 32];  // 2 x 8 KB
  const int tid = threadIdx.x;
  const int wave = tid >> 6, lane = tid & 63;
  const int quad = lane >> 4, l16 = lane & 15;
  const int wm = wave >> 1, wn = wave & 1;
  const int m0 = blockIdx.x * 64;
  const int n0 = blockIdx.y * 128;
  const int mb = m0 + wm * 32, nb = n0 + wn * 64;

  f32x4 acc[2][4];
#pragma unroll
  for (int i = 0; i < 2; i++)
#pragma unroll
    for (int j = 0; j < 4; j++) acc[i][j] = f32x4{0.f, 0.f, 0.f, 0.f};

  const int sA0 = wave * 64 + lane;
  const int rowA = sA0 >> 2, cgA = (sA0 & 3) ^ swz(rowA);
  const size_t agl = (size_t)(m0 + rowA) * 512 + cgA * 8;
  int rowB[2], cgB[2];
#pragma unroll
  for (int rnd = 0; rnd < 2; ++rnd) {
    int s = rnd * 256 + sA0;
    rowB[rnd] = s >> 2;
    cgB[rnd] = (s & 3) ^ swz(rowB[rnd]);
  }
  const size_t bgl0 = (size_t)(n0 + rowB[0]) * 512 + cgB[0] * 8;
  const size_t bgl1 = (size_t)(n0 + rowB[1]) * 512 + cgB[1] * 8;

  // frag bases (kt-invariant)
  int kbA[2], kbB[4];
#pragma unroll
  for (int mi = 0; mi < 2; ++mi) {
    int r = wm * 32 + mi * 16 + l16;
    kbA[mi] = r * 32 + (quad ^ swz(r)) * 8;
  }
#pragma unroll
  for (int ni = 0; ni < 4; ++ni) {
    int r = wn * 64 + ni * 16 + l16;
    kbB[ni] = r * 32 + (quad ^ swz(r)) * 8;
  }

  // prologue: stage kt=0 into buf 0
  GLL(A + agl, &As[0][(wave * 64) * 8]);
  GLL(Bt + bgl0, &Bs[0][(wave * 64) * 8]);
  GLL(Bt + bgl1, &Bs[0][(256 + wave * 64) * 8]);

#pragma unroll 2
  for (int kt = 0; kt < 16; ++kt) {
    __syncthreads();
    const u16* AsB = As[kt & 1];
    const u16* BsB = Bs[kt & 1];
    if (kt + 1 < 16) {
      u16* AsN = (u16*)As[(kt & 1) ^ 1];
      u16* BsN = (u16*)Bs[(kt & 1) ^ 1];
      const int k1 = (kt + 1) * 32;
      GLL(A + agl + k1, AsN + (wave * 64) * 8);
      GLL(Bt + bgl0 + k1, BsN + (wave * 64) * 8);
      GLL(Bt + bgl1 + k1, BsN + (256 + wave * 64) * 8);
    }

    bf16x8 af[2], bf_[4];
#pragma unroll
    for (int mi = 0; mi < 2; ++mi) af[mi] = ld8(AsB + kbA[mi]);
#pragma unroll
    for (int ni = 0; ni < 4; ++ni) bf_[ni] = ld8(BsB + kbB[ni]);
#pragma unroll
    for (int mi = 0; mi < 2; ++mi)
#pragma unroll
      for (int ni = 0; ni < 4; ++ni)
        acc[mi][ni] = __builtin_amdgcn_mfma_f32_16x16x32_bf16(
            af[mi], bf_[ni], acc[mi][ni], 0, 0, 0);
  }

  // Epilogue: split Q/K/V^T
#pragma unroll
  for (int mi = 0; mi < 2; ++mi) {
#pragma unroll
    for (int ni = 0; ni < 4; ++ni) {
      f32x4 a = acc[mi][ni];
      int r0 = mb + mi * 16 + quad * 4;
      int c = nb + ni * 16 + l16;
      if (c < 512) {
        const float C2 = 0.06375871506958306f;  // 512^-0.5 * log2(e)
#pragma unroll
        for (int g = 0; g < 4; ++g) outq[(size_t)(r0 + g) * 512 + c] = f2b(a[g] * C2);
      } else if (c < 1024) {
#pragma unroll
        for (int g = 0; g < 4; ++g) outk[(size_t)(r0 + g) * 512 + (c - 512)] = f2b(a[g]);
      } else {
        int cv = c - 1024, hh = cv >> 6, dd = cv & 63;
        int bb = r0 >> 11, nt = r0 & 2047;
        u32x2 pk;
        pk[0] = (unsigned)f2b(a[0]) | ((unsigned)f2b(a[1]) << 16);
        pk[1] = (unsigned)f2b(a[2]) | ((unsigned)f2b(a[3]) << 16);
        *(u32x2*)&outvt[((size_t)(bb * 8 + hh) * 64 + dd) * 2048 + nt] = pk;
      }
    }
  }
}

// ---------------------------------------------------------------------------
// Flash attention v7 (2x2 split). grid (32 bh, 32 qt) -> XCD = bh%8.
// PV uses full-rate 16x16x32 MFMA with k<->kv mapping
//   k = quad*8 + t*4 + g  <->  kv = kvs*32 + t*16 + quad*4 + g
// (a) softmax denominator via ones-MFMA (l = ones x P); (b) all 8 QK MFMAs
// issue before the exp phase.
// ---------------------------------------------------------------------------
__global__ __launch_bounds__(256, 4) void attn_k(const u16* __restrict__ q,
                                                 const u16* __restrict__ k,
                                                 const u16* __restrict__ vt,
                                                 u16* __restrict__ o) {
  __shared__ __align__(16) u16 Ks[2][64 * 64];   // 16 KB
  __shared__ __align__(16) u16 Vs[2][64 * 64];   // 16 KB
  __shared__ float Lr[4][32];                    // 512 B
  const int tid = threadIdx.x, wave = tid >> 6, lane = tid & 63;
  const int quad = lane >> 4, l16 = lane & 15;
  const int swl = l16 & 7;
  const int qh2 = wave & 1, kvs = wave >> 1;
  const int bh = blockIdx.x, b = bh >> 3, h = bh & 7;
  const int qt0 = blockIdx.y * 64;

  const u16* qpb = q + (size_t)(b * 2048 + qt0 + qh2 * 32) * 512 + h * 64;
  bf16x8 aq[2][2];
#pragma unroll
  for (int qt = 0; qt < 2; ++qt) {
    const u16* qp = qpb + (size_t)(qt * 16 + l16) * 512;
    aq[qt][0] = ld8(qp + quad * 8);
    aq[qt][1] = ld8(qp + 32 + quad * 8);
  }

  const u16* kp = k + (size_t)b * 2048 * 512 + h * 64;
  const u16* vp = vt + (size_t)bh * 64 * 2048;

  const int srow = lane >> 3, schk = lane & 7, sgc = schk ^ srow;
  const int krow0 = wave * 8 + srow;
  const size_t kgl0 = (size_t)krow0 * 512 + sgc * 8;
  const size_t kgl1 = (size_t)(krow0 + 32) * 512 + sgc * 8;
  const size_t vgl0 = (size_t)krow0 * 2048 + sgc * 8;
  const size_t vgl1 = (size_t)(krow0 + 32) * 2048 + sgc * 8;

  int kb[2][2];
#pragma unroll
  for (int t = 0; t < 2; ++t) {
    kb[t][0] = (kvs * 32 + t * 16 + l16) * 64 + ((quad)     ^ swl) * 8;
    kb[t][1] = (kvs * 32 + t * 16 + l16) * 64 + ((4 + quad) ^ swl) * 8;
  }
  // V^T fragment bases: row l16 (+dt*16), col chunks (kv units of 8):
  const int vblo = l16 * 64 + (((kvs << 2) + (quad >> 1)) ^ swl) * 8 + (quad & 1) * 4;
  const int vbhi = l16 * 64 + (((kvs << 2) + 2 + (quad >> 1)) ^ swl) * 8 + (quad & 1) * 4;

  f32x4 oacc[4][2];
#pragma unroll
  for (int i = 0; i < 4; i++)
#pragma unroll
    for (int j = 0; j < 2; j++) oacc[i][j] = f32x4{0.f, 0.f, 0.f, 0.f};
  f32x4 lsacc[2];
  lsacc[0] = f32x4{0.f, 0.f, 0.f, 0.f};
  lsacc[1] = f32x4{0.f, 0.f, 0.f, 0.f};

  // bf16 ones vector for the denominator MFMA
  u32x4 onesw;
  onesw[0] = 0x3F803F80u; onesw[1] = 0x3F803F80u;
  onesw[2] = 0x3F803F80u; onesw[3] = 0x3F803F80u;
  bf16x8 onesf; __builtin_memcpy(&onesf, &onesw, 16);

  GLL(kp + kgl0, &Ks[0][(wave * 8) * 64]);
  GLL(kp + kgl1, &Ks[0][(32 + wave * 8) * 64]);
  GLL(vp + vgl0, &Vs[0][(wave * 8) * 64]);
  GLL(vp + vgl1, &Vs[0][(32 + wave * 8) * 64]);

#pragma unroll 2
  for (int kt = 0; kt < 32; ++kt) {
    __syncthreads();
    const u16* KsB = Ks[kt & 1];
    const u16* VsB = Vs[kt & 1];
    if (kt + 1 < 32) {
      u16* KsN = (u16*)Ks[(kt & 1) ^ 1];
      u16* VsN = (u16*)Vs[(kt & 1) ^ 1];
      const u16* kpn = kp + (size_t)(kt + 1) * 32768;
      const u16* vpn = vp + (size_t)(kt + 1) * 64;
      GLL(kpn + kgl0, KsN + (wave * 8) * 64);
      GLL(kpn + kgl1, KsN + (32 + wave * 8) * 64);
      GLL(vpn + vgl0, VsN + (wave * 8) * 64);
      GLL(vpn + vgl1, VsN + (32 + wave * 8) * 64);
    }

    // ---- K fragments, then all QK MFMAs back-to-back ----
    bf16x8 kf[2][2];
#pragma unroll
    for (int t = 0; t < 2; ++t) {
      kf[t][0] = ld8(KsB + kb[t][0]);
      kf[t][1] = ld8(KsB + kb[t][1]);
    }
    f32x4 sa[2][2];
    __builtin_amdgcn_s_setprio(1);
#pragma unroll
    for (int t = 0; t < 2; ++t)
#pragma unroll
      for (int qt = 0; qt < 2; ++qt) {
        f32x4 z = f32x4{0.f, 0.f, 0.f, 0.f};
        z = __builtin_amdgcn_mfma_f32_16x16x32_bf16(kf[t][0], aq[qt][0], z, 0, 0, 0);
        z = __builtin_amdgcn_mfma_f32_16x16x32_bf16(kf[t][1], aq[qt][1], z, 0, 0, 0);
        sa[t][qt] = z;
      }
    __builtin_amdgcn_s_setprio(0);

    // ---- exp + pack into P fragments (j=0..3 <- t=0, j=4..7 <- t=1) ----
    u32x4 pw[2];
#pragma unroll
    for (int t = 0; t < 2; ++t)
#pragma unroll
      for (int qt = 0; qt < 2; ++qt) {
        float p0 = __builtin_amdgcn_exp2f(sa[t][qt][0]);
        float p1 = __builtin_amdgcn_exp2f(sa[t][qt][1]);
        float p2 = __builtin_amdgcn_exp2f(sa[t][qt][2]);
        float p3 = __builtin_amdgcn_exp2f(sa[t][qt][3]);
        pw[qt][t * 2]     = pkhi(p1, p0);
        pw[qt][t * 2 + 1] = pkhi(p3, p2);
      }
    bf16x8 pf[2];
    __builtin_memcpy(&pf[0], &pw[0], 16);
    __builtin_memcpy(&pf[1], &pw[1], 16);

    // ---- PV + denominator MFMAs ----
    __builtin_amdgcn_s_setprio(1);
#pragma unroll
    for (int dt = 0; dt < 4; ++dt) {
      u32x2 lo = *(const u32x2*)(VsB + vblo + dt * 1024);
      u32x2 hi = *(const u32x2*)(VsB + vbhi + dt * 1024);
      u32x4 w;
      w[0] = lo[0]; w[1] = lo[1]; w[2] = hi[0]; w[3] = hi[1];
      bf16x8 av; __builtin_memcpy(&av, &w, 16);
#pragma unroll
      for (int qt = 0; qt < 2; ++qt)
        oacc[dt][qt] = __builtin_amdgcn_mfma_f32_16x16x32_bf16(
            av, pf[qt], oacc[dt][qt], 0, 0, 0);
    }
#pragma unroll
    for (int qt = 0; qt < 2; ++qt)
      lsacc[qt] = __builtin_amdgcn_mfma_f32_16x16x32_bf16(
          onesf, pf[qt], lsacc[qt], 0, 0, 0);
    __builtin_amdgcn_s_setprio(0);
  }

  // lsacc[qt][g] = full sum over this wave's kv half for q-row qt*16+l16
  if (quad == 0) {
#pragma unroll
    for (int qt = 0; qt < 2; ++qt) Lr[wave][qt * 16 + l16] = lsacc[qt][0];
  }
  __syncthreads();

  float* R = (float*)&Ks[0][0];
  const int l7 = lane & 7;
  if (wave >= 2) {
    float* Rw = R + (wave - 2) * 2048;
#pragma unroll
    for (int dt = 0; dt < 4; ++dt)
#pragma unroll
      for (int qt = 0; qt < 2; ++qt) {
        int s = (dt * 2 + qt) ^ l7;
        *(f32x4*)&Rw[lane * 32 + s * 4] = oacc[dt][qt];
      }
  }
  __syncthreads();
  if (wave < 2) {
    float* Rw = R + wave * 2048;
    float inv[2];
#pragma unroll
    for (int qt = 0; qt < 2; ++qt)
      inv[qt] = 1.0f / (Lr[wave][qt * 16 + l16] + Lr[wave + 2][qt * 16 + l16]);
#pragma unroll
    for (int dt = 0; dt < 4; ++dt)
#pragma unroll
      for (int qt = 0; qt < 2; ++qt) {
        int s = (dt * 2 + qt) ^ l7;
        f32x4 v = *(f32x4*)&Rw[lane * 32 + s * 4];
        float i4 = inv[qt];
        float o0 = (oacc[dt][qt][0] + v[0]) * i4;
        float o1 = (oacc[dt][qt][1] + v[1]) * i4;
        float o2 = (oacc[dt][qt][2] + v[2]) * i4;
        float o3 = (oacc[dt][qt][3] + v[3]) * i4;
        u16* op = o + (size_t)(b * 2048 + qt0 + wave * 32 + qt * 16 + l16) * 512 +
                  h * 64 + dt * 16 + quad * 4;
        u32x2 pk;
        pk[0] = (unsigned)f2b(o0) | ((unsigned)f2b(o1) << 16);
        pk[1] = (unsigned)f2b(o2) | ((unsigned)f2b(o3) << 16);
        *(u32x2*)op = pk;
      }
  }
}

// ---------------------------------------------------------------------------
extern "C" void kernel_launch(void* const* d_in, const int* in_sizes, int n_in,
                              void* d_out, int out_size, void* d_ws,
                              size_t ws_size, hipStream_t stream) {
  const float* x   = (const float*)d_in[0];
  const float* Wq  = (const float*)d_in[1];
  const float* Wk  = (const float*)d_in[2];
  const float* Wv  = (const float*)d_in[3];
  const float* Wo  = (const float*)d_in[4];
  const float* bo  = (const float*)d_in[5];
  const float* g1  = (const float*)d_in[6];
  const float* bg1 = (const float*)d_in[7];
  const float* W1  = (const float*)d_in[8];
  const float* b1  = (const float*)d_in[9];
  const float* W2  = (const float*)d_in[10];
  const float* b2  = (const float*)d_in[11];
  const float* g2  = (const float*)d_in[12];
  const float* bg2 = (const float*)d_in[13];

  char* ws = (char*)d_ws;
  float* h    = (float*)ws;                        // 16 MB fp32 residual
  u16* yb     = (u16*)(ws + (16ll << 20));         // 8 MB LN output (bf16)
  u16* qb     = (u16*)(ws + (24ll << 20));         // 8 MB q / ffn-intermediate
  u16* kb     = (u16*)(ws + (32ll << 20));         // 8 MB k
  u16* vtb    = (u16*)(ws + (40ll << 20));         // 8 MB v transposed [b,h,d,n]
  u16* ob     = (u16*)(ws + (48ll << 20));         // 8 MB attn out
  u16* wtqkv  = (u16*)(ws + (56ll << 20));         // 6 MB [l][1536][512] bf16
  u16* wto    = (u16*)(ws + (62ll << 20));         // 2 MB
  u16* wt1    = (u16*)(ws + (64ll << 20));         // 2 MB
  u16* wt2    = (u16*)(ws + (66ll << 20));         // 2 MB  (total 68 MB)

  tr_all_k<<<dim3(16, 16, 24), dim3(32, 8), 0, stream>>>(
      Wq, Wk, Wv, Wo, W1, W2, wtqkv, wto, wt1, wt2);

  for (int l = 0; l < 4; ++l) {
    const float* hsrc = (l == 0) ? x : h;
    ln_k<<<2048, 256, 0, stream>>>(hsrc, g1 + l * 512, bg1 + l * 512, yb);
    gemm_qkv_k<<<dim3(128, 12), 256, 0, stream>>>(
        yb, wtqkv + l * 786432, qb, kb, vtb);
    attn_k<<<dim3(32, 32), 256, 0, stream>>>(qb, kb, vtb, ob);
    gemm2_k<EPI_RES><<<dim3(128, 4), 512, 0, stream>>>(
        ob, wto + l * 262144, bo + l * 512, nullptr, hsrc, h, nullptr);
    ln_k<<<2048, 256, 0, stream>>>(h, g2 + l * 512, bg2 + l * 512, yb);
    gemm2_k<EPI_GELU><<<dim3(128, 4), 512, 0, stream>>>(
        yb, wt1 + l * 262144, b1 + l * 512, qb, nullptr, nullptr, nullptr);
    gemm2_k<EPI_RES><<<dim3(128, 4), 512, 0, stream>>>(
        qb, wt2 + l * 262144, b2 + l * 512, nullptr, h, h,
        (l == 3) ? (float*)d_out : nullptr);
  }
}

// Round 7
// 546.179 us; speedup vs baseline: 1.1264x; 1.0793x over previous
//
#include <hip/hip_runtime.h>
#include <hip/hip_bf16.h>

// Problem: L=4 B=4 N=2048 D=512 H=8 HD=64. Inputs/outputs FP32.
// Weights transposed+cast to bf16 once; bf16 MFMA, fp32 accumulate; fp32
// residual stream. scale = 512^-0.5 (D**-0.5 per ref).
// Round 16: non-attn kernels are ~398us vs ~114us BW roofline ->
// HBM-LATENCY-bound (16 serial barrier rounds at BK=32, ~150cy compute vs
// ~700cy load latency per round). Fix: BK=64 (8 rounds, 2x bytes/round).
// 8-chunk XOR swizzle: LDS slot c holds global chunk c^(r&7); fragment
// read at (ks*4+quad)^(r&7). gemm2 + gemm_qkv both 512 thr / 2x4 waves /
// 32x32 wave-tile / 48 KB LDS. attn v7 unchanged (47.7us best).

typedef __bf16 bf16x8 __attribute__((ext_vector_type(8)));
typedef float f32x4 __attribute__((ext_vector_type(4)));
typedef unsigned int u32x4 __attribute__((ext_vector_type(4)));
typedef unsigned int u32x2 __attribute__((ext_vector_type(2)));
typedef unsigned short u16;

__device__ __forceinline__ u16 f2b(float f) {  // RNE (values are finite)
  unsigned int u; __builtin_memcpy(&u, &f, 4);
  u += 0x7fffu + ((u >> 16) & 1u);
  return (u16)(u >> 16);
}
__device__ __forceinline__ bf16x8 ld8(const u16* p) {
  u32x4 t = *(const u32x4*)p;
  bf16x8 r; __builtin_memcpy(&r, &t, 16); return r;
}
__device__ __forceinline__ unsigned pkhi(float a, float b) {
  unsigned ua, ub; __builtin_memcpy(&ua, &a, 4); __builtin_memcpy(&ub, &b, 4);
  return __builtin_amdgcn_perm(ua, ub, 0x07060302u);
}

#define GLL(gp, lp) __builtin_amdgcn_global_load_lds( \
    (const __attribute__((address_space(1))) void*)(gp), \
    (__attribute__((address_space(3))) void*)(lp), 16, 0, 0)

__device__ __forceinline__ int swz(int r) { return (r + (r >> 2)) & 3; }

// ---------------------------------------------------------------------------
// All weight transposes in one launch. grid (16,16,24): z -> which(6) x l(4).
// out[l][n][k] = bf16(in[l][k][n]).
// ---------------------------------------------------------------------------
__global__ __launch_bounds__(256) void tr_all_k(
    const float* __restrict__ Wq, const float* __restrict__ Wk,
    const float* __restrict__ Wv, const float* __restrict__ Wo,
    const float* __restrict__ W1, const float* __restrict__ W2,
    u16* __restrict__ wtqkv, u16* __restrict__ wto,
    u16* __restrict__ wt1, u16* __restrict__ wt2) {
  __shared__ float t[32][33];
  int tx = threadIdx.x, ty = threadIdx.y;
  int z = blockIdx.z, which = z >> 2, l = z & 3;
  const float* in;
  u16* out;
  switch (which) {
    case 0: in = Wq; out = wtqkv + l * 786432; break;
    case 1: in = Wk; out = wtqkv + l * 786432 + 262144; break;
    case 2: in = Wv; out = wtqkv + l * 786432 + 524288; break;
    case 3: in = Wo; out = wto + l * 262144; break;
    case 4: in = W1; out = wt1 + l * 262144; break;
    default: in = W2; out = wt2 + l * 262144; break;
  }
  int k0 = blockIdx.y * 32, n0 = blockIdx.x * 32;
  const float* ip = in + l * 262144;
#pragma unroll
  for (int i = 0; i < 4; i++)
    t[ty + i * 8][tx] = ip[(k0 + ty + i * 8) * 512 + n0 + tx];
  __syncthreads();
#pragma unroll
  for (int i = 0; i < 4; i++)
    out[(n0 + ty + i * 8) * 512 + k0 + tx] = f2b(t[tx][ty + i * 8]);
}

// ---------------------------------------------------------------------------
// LayerNorm: one wave per token (D=512, 8 elems/lane), fp32 in, bf16 out
// ---------------------------------------------------------------------------
__global__ __launch_bounds__(256) void ln_k(const float* __restrict__ h,
                                            const float* __restrict__ gg,
                                            const float* __restrict__ bb,
                                            u16* __restrict__ y) {
  int tid = threadIdx.x, wave = tid >> 6, lane = tid & 63;
  int tok = blockIdx.x * 4 + wave;
  const float* hp = h + (size_t)tok * 512 + lane * 8;
  float x[8];
  *(float4*)&x[0] = *(const float4*)hp;
  *(float4*)&x[4] = *(const float4*)(hp + 4);
  float s = 0.f, ss = 0.f;
#pragma unroll
  for (int i = 0; i < 8; i++) { s += x[i]; ss += x[i] * x[i]; }
#pragma unroll
  for (int off = 1; off < 64; off <<= 1) {
    s += __shfl_xor(s, off, 64);
    ss += __shfl_xor(ss, off, 64);
  }
  float mean = s * (1.0f / 512.0f);
  float var = ss * (1.0f / 512.0f) - mean * mean;
  float rstd = rsqrtf(var + 1e-5f);
  u32x4 ov;
#pragma unroll
  for (int i = 0; i < 4; i++) {
    int d0 = lane * 8 + i * 2;
    float y0 = (x[i * 2]     - mean) * rstd * gg[d0]     + bb[d0];
    float y1 = (x[i * 2 + 1] - mean) * rstd * gg[d0 + 1] + bb[d0 + 1];
    ov[i] = (unsigned)f2b(y0) | ((unsigned)f2b(y1) << 16);
  }
  *(u32x4*)&y[(size_t)tok * 512 + lane * 8] = ov;
}

// ---------------------------------------------------------------------------
// GEMM2 v4: 64x128 tile, BK=64, 8 K-rounds, double-buffered, 48 KB LDS,
// 512 threads (2x4 waves, wave-tile 32x32). grid (128 m, 4 n) -> 2/CU.
// Staging per kt: A 512 segs (1 GLL), B 1024 segs (2 GLL). 8-chunk XOR
// swizzle (slot c holds global chunk c^(r&7)). RES preloads hin tile.
// ---------------------------------------------------------------------------
enum { EPI_RES = 1, EPI_GELU = 2 };

template <int EPI>
__global__ __launch_bounds__(512, 4) void gemm2_k(
    const u16* __restrict__ A, const u16* __restrict__ Bt,
    const float* __restrict__ bias, u16* __restrict__ out0,
    const float* __restrict__ hin, float* __restrict__ hout,
    float* __restrict__ fout) {
  __shared__ __align__(16) u16 As[2][64 * 64];   // 2 x 8 KB
  __shared__ __align__(16) u16 Bs[2][128 * 64];  // 2 x 16 KB
  const int tid = threadIdx.x;
  const int wave = tid >> 6, lane = tid & 63;
  const int quad = lane >> 4, l16 = lane & 15;
  const int wm = wave >> 2, wn = wave & 3;
  const int m0 = blockIdx.x * 64;
  const int n0 = blockIdx.y * 128;
  const int mb = m0 + wm * 32, nb = n0 + wn * 32;

  // hin residual tile -> regs (RES only); completes during the main loop
  float hr[2][2][4];
  if constexpr (EPI == EPI_RES) {
#pragma unroll
    for (int mi = 0; mi < 2; ++mi)
#pragma unroll
      for (int ni = 0; ni < 2; ++ni) {
        int r0 = mb + mi * 16 + quad * 4, c = nb + ni * 16 + l16;
#pragma unroll
        for (int g = 0; g < 4; ++g)
          hr[mi][ni][g] = hin[(size_t)(r0 + g) * 512 + c];
      }
  }

  f32x4 acc[2][2];
#pragma unroll
  for (int i = 0; i < 2; i++)
#pragma unroll
    for (int j = 0; j < 2; j++) acc[i][j] = f32x4{0.f, 0.f, 0.f, 0.f};

  // A: 64 rows x 8 chunks = 512 segs (1 round); B: 128 x 8 = 1024 (2 rounds)
  const int rowA = tid >> 3, cgA = (tid & 7) ^ (rowA & 7);
  const size_t agl = (size_t)(m0 + rowA) * 512 + cgA * 8;
  int rowB[2], cgB[2];
#pragma unroll
  for (int rnd = 0; rnd < 2; ++rnd) {
    int s = rnd * 512 + tid;
    rowB[rnd] = s >> 3;
    cgB[rnd] = (tid & 7) ^ (rowB[rnd] & 7);
  }
  const size_t bgl0 = (size_t)(n0 + rowB[0]) * 512 + cgB[0] * 8;
  const size_t bgl1 = (size_t)(n0 + rowB[1]) * 512 + cgB[1] * 8;

  // frag bases (kt-invariant): [mi/ni][ks]
  int kbA[2][2], kbB[2][2];
#pragma unroll
  for (int mi = 0; mi < 2; ++mi) {
    int r = wm * 32 + mi * 16 + l16;
#pragma unroll
    for (int ks = 0; ks < 2; ++ks)
      kbA[mi][ks] = r * 64 + ((ks * 4 + quad) ^ (r & 7)) * 8;
  }
#pragma unroll
  for (int ni = 0; ni < 2; ++ni) {
    int r = wn * 32 + ni * 16 + l16;
#pragma unroll
    for (int ks = 0; ks < 2; ++ks)
      kbB[ni][ks] = r * 64 + ((ks * 4 + quad) ^ (r & 7)) * 8;
  }

  // prologue: stage kt=0 into buf 0
  GLL(A + agl, &As[0][(wave * 64) * 8]);
  GLL(Bt + bgl0, &Bs[0][(wave * 64) * 8]);
  GLL(Bt + bgl1, &Bs[0][(512 + wave * 64) * 8]);

#pragma unroll 2
  for (int kt = 0; kt < 8; ++kt) {
    __syncthreads();
    const u16* AsB = As[kt & 1];
    const u16* BsB = Bs[kt & 1];
    if (kt + 1 < 8) {
      u16* AsN = (u16*)As[(kt & 1) ^ 1];
      u16* BsN = (u16*)Bs[(kt & 1) ^ 1];
      const int k1 = (kt + 1) * 64;
      GLL(A + agl + k1, AsN + (wave * 64) * 8);
      GLL(Bt + bgl0 + k1, BsN + (wave * 64) * 8);
      GLL(Bt + bgl1 + k1, BsN + (512 + wave * 64) * 8);
    }

#pragma unroll
    for (int ks = 0; ks < 2; ++ks) {
      bf16x8 af[2], bf_[2];
#pragma unroll
      for (int mi = 0; mi < 2; ++mi) af[mi] = ld8(AsB + kbA[mi][ks]);
#pragma unroll
      for (int ni = 0; ni < 2; ++ni) bf_[ni] = ld8(BsB + kbB[ni][ks]);
#pragma unroll
      for (int mi = 0; mi < 2; ++mi)
#pragma unroll
        for (int ni = 0; ni < 2; ++ni)
          acc[mi][ni] = __builtin_amdgcn_mfma_f32_16x16x32_bf16(
              af[mi], bf_[ni], acc[mi][ni], 0, 0, 0);
    }
  }

  // Epilogue. C layout: row = quad*4+reg, col = l16.
#pragma unroll
  for (int mi = 0; mi < 2; ++mi) {
#pragma unroll
    for (int ni = 0; ni < 2; ++ni) {
      f32x4 a = acc[mi][ni];
      int r0 = mb + mi * 16 + quad * 4;
      int c = nb + ni * 16 + l16;
      float bi = bias[c];
      if constexpr (EPI == EPI_RES) {
#pragma unroll
        for (int g = 0; g < 4; ++g) {
          float v = hr[mi][ni][g] + a[g] + bi;
          hout[(size_t)(r0 + g) * 512 + c] = v;
          if (fout) fout[(size_t)(r0 + g) * 512 + c] = v;
        }
      } else {  // GELU
#pragma unroll
        for (int g = 0; g < 4; ++g) {
          float t = a[g] + bi;
          float gl = 0.5f * t * (1.0f + erff(t * 0.70710678118654752f));
          out0[(size_t)(r0 + g) * 512 + c] = f2b(gl);
        }
      }
    }
  }
}

// ---------------------------------------------------------------------------
// QKV GEMM v3: 64x128 tile, BK=64, 8 K-rounds, dbuf, 48 KB LDS, 512 thr.
// grid (128 m, 12 n) -> 1536 blocks; LDS-limited 3 blocks/CU resident
// (launch_bounds(512,6)). Epilogue splits Q (pre-scaled), K, V^T.
// ---------------------------------------------------------------------------
__global__ __launch_bounds__(512, 6) void gemm_qkv_k(
    const u16* __restrict__ A, const u16* __restrict__ Bt,
    u16* __restrict__ outq, u16* __restrict__ outk, u16* __restrict__ outvt) {
  __shared__ __align__(16) u16 As[2][64 * 64];   // 2 x 8 KB
  __shared__ __align__(16) u16 Bs[2][128 * 64];  // 2 x 16 KB
  const int tid = threadIdx.x;
  const int wave = tid >> 6, lane = tid & 63;
  const int quad = lane >> 4, l16 = lane & 15;
  const int wm = wave >> 2, wn = wave & 3;
  const int m0 = blockIdx.x * 64;
  const int n0 = blockIdx.y * 128;
  const int mb = m0 + wm * 32, nb = n0 + wn * 32;

  f32x4 acc[2][2];
#pragma unroll
  for (int i = 0; i < 2; i++)
#pragma unroll
    for (int j = 0; j < 2; j++) acc[i][j] = f32x4{0.f, 0.f, 0.f, 0.f};

  const int rowA = tid >> 3, cgA = (tid & 7) ^ (rowA & 7);
  const size_t agl = (size_t)(m0 + rowA) * 512 + cgA * 8;
  int rowB[2], cgB[2];
#pragma unroll
  for (int rnd = 0; rnd < 2; ++rnd) {
    int s = rnd * 512 + tid;
    rowB[rnd] = s >> 3;
    cgB[rnd] = (tid & 7) ^ (rowB[rnd] & 7);
  }
  const size_t bgl0 = (size_t)(n0 + rowB[0]) * 512 + cgB[0] * 8;
  const size_t bgl1 = (size_t)(n0 + rowB[1]) * 512 + cgB[1] * 8;

  int kbA[2][2], kbB[2][2];
#pragma unroll
  for (int mi = 0; mi < 2; ++mi) {
    int r = wm * 32 + mi * 16 + l16;
#pragma unroll
    for (int ks = 0; ks < 2; ++ks)
      kbA[mi][ks] = r * 64 + ((ks * 4 + quad) ^ (r & 7)) * 8;
  }
#pragma unroll
  for (int ni = 0; ni < 2; ++ni) {
    int r = wn * 32 + ni * 16 + l16;
#pragma unroll
    for (int ks = 0; ks < 2; ++ks)
      kbB[ni][ks] = r * 64 + ((ks * 4 + quad) ^ (r & 7)) * 8;
  }

  // prologue: stage kt=0 into buf 0
  GLL(A + agl, &As[0][(wave * 64) * 8]);
  GLL(Bt + bgl0, &Bs[0][(wave * 64) * 8]);
  GLL(Bt + bgl1, &Bs[0][(512 + wave * 64) * 8]);

#pragma unroll 2
  for (int kt = 0; kt < 8; ++kt) {
    __syncthreads();
    const u16* AsB = As[kt & 1];
    const u16* BsB = Bs[kt & 1];
    if (kt + 1 < 8) {
      u16* AsN = (u16*)As[(kt & 1) ^ 1];
      u16* BsN = (u16*)Bs[(kt & 1) ^ 1];
      const int k1 = (kt + 1) * 64;
      GLL(A + agl + k1, AsN + (wave * 64) * 8);
      GLL(Bt + bgl0 + k1, BsN + (wave * 64) * 8);
      GLL(Bt + bgl1 + k1, BsN + (512 + wave * 64) * 8);
    }

#pragma unroll
    for (int ks = 0; ks < 2; ++ks) {
      bf16x8 af[2], bf_[2];
#pragma unroll
      for (int mi = 0; mi < 2; ++mi) af[mi] = ld8(AsB + kbA[mi][ks]);
#pragma unroll
      for (int ni = 0; ni < 2; ++ni) bf_[ni] = ld8(BsB + kbB[ni][ks]);
#pragma unroll
      for (int mi = 0; mi < 2; ++mi)
#pragma unroll
        for (int ni = 0; ni < 2; ++ni)
          acc[mi][ni] = __builtin_amdgcn_mfma_f32_16x16x32_bf16(
              af[mi], bf_[ni], acc[mi][ni], 0, 0, 0);
    }
  }

  // Epilogue: split Q/K/V^T
#pragma unroll
  for (int mi = 0; mi < 2; ++mi) {
#pragma unroll
    for (int ni = 0; ni < 2; ++ni) {
      f32x4 a = acc[mi][ni];
      int r0 = mb + mi * 16 + quad * 4;
      int c = nb + ni * 16 + l16;
      if (c < 512) {
        const float C2 = 0.06375871506958306f;  // 512^-0.5 * log2(e)
#pragma unroll
        for (int g = 0; g < 4; ++g) outq[(size_t)(r0 + g) * 512 + c] = f2b(a[g] * C2);
      } else if (c < 1024) {
#pragma unroll
        for (int g = 0; g < 4; ++g) outk[(size_t)(r0 + g) * 512 + (c - 512)] = f2b(a[g]);
      } else {
        int cv = c - 1024, hh = cv >> 6, dd = cv & 63;
        int bb = r0 >> 11, nt = r0 & 2047;
        u32x2 pk;
        pk[0] = (unsigned)f2b(a[0]) | ((unsigned)f2b(a[1]) << 16);
        pk[1] = (unsigned)f2b(a[2]) | ((unsigned)f2b(a[3]) << 16);
        *(u32x2*)&outvt[((size_t)(bb * 8 + hh) * 64 + dd) * 2048 + nt] = pk;
      }
    }
  }
}

// ---------------------------------------------------------------------------
// Flash attention v7 (2x2 split). grid (32 bh, 32 qt) -> XCD = bh%8.
// PV uses full-rate 16x16x32 MFMA with k<->kv mapping
//   k = quad*8 + t*4 + g  <->  kv = kvs*32 + t*16 + quad*4 + g
// (a) softmax denominator via ones-MFMA (l = ones x P); (b) all 8 QK MFMAs
// issue before the exp phase.
// ---------------------------------------------------------------------------
__global__ __launch_bounds__(256, 4) void attn_k(const u16* __restrict__ q,
                                                 const u16* __restrict__ k,
                                                 const u16* __restrict__ vt,
                                                 u16* __restrict__ o) {
  __shared__ __align__(16) u16 Ks[2][64 * 64];   // 16 KB
  __shared__ __align__(16) u16 Vs[2][64 * 64];   // 16 KB
  __shared__ float Lr[4][32];                    // 512 B
  const int tid = threadIdx.x, wave = tid >> 6, lane = tid & 63;
  const int quad = lane >> 4, l16 = lane & 15;
  const int swl = l16 & 7;
  const int qh2 = wave & 1, kvs = wave >> 1;
  const int bh = blockIdx.x, b = bh >> 3, h = bh & 7;
  const int qt0 = blockIdx.y * 64;

  const u16* qpb = q + (size_t)(b * 2048 + qt0 + qh2 * 32) * 512 + h * 64;
  bf16x8 aq[2][2];
#pragma unroll
  for (int qt = 0; qt < 2; ++qt) {
    const u16* qp = qpb + (size_t)(qt * 16 + l16) * 512;
    aq[qt][0] = ld8(qp + quad * 8);
    aq[qt][1] = ld8(qp + 32 + quad * 8);
  }

  const u16* kp = k + (size_t)b * 2048 * 512 + h * 64;
  const u16* vp = vt + (size_t)bh * 64 * 2048;

  const int srow = lane >> 3, schk = lane & 7, sgc = schk ^ srow;
  const int krow0 = wave * 8 + srow;
  const size_t kgl0 = (size_t)krow0 * 512 + sgc * 8;
  const size_t kgl1 = (size_t)(krow0 + 32) * 512 + sgc * 8;
  const size_t vgl0 = (size_t)krow0 * 2048 + sgc * 8;
  const size_t vgl1 = (size_t)(krow0 + 32) * 2048 + sgc * 8;

  int kb[2][2];
#pragma unroll
  for (int t = 0; t < 2; ++t) {
    kb[t][0] = (kvs * 32 + t * 16 + l16) * 64 + ((quad)     ^ swl) * 8;
    kb[t][1] = (kvs * 32 + t * 16 + l16) * 64 + ((4 + quad) ^ swl) * 8;
  }
  // V^T fragment bases: row l16 (+dt*16), col chunks (kv units of 8):
  const int vblo = l16 * 64 + (((kvs << 2) + (quad >> 1)) ^ swl) * 8 + (quad & 1) * 4;
  const int vbhi = l16 * 64 + (((kvs << 2) + 2 + (quad >> 1)) ^ swl) * 8 + (quad & 1) * 4;

  f32x4 oacc[4][2];
#pragma unroll
  for (int i = 0; i < 4; i++)
#pragma unroll
    for (int j = 0; j < 2; j++) oacc[i][j] = f32x4{0.f, 0.f, 0.f, 0.f};
  f32x4 lsacc[2];
  lsacc[0] = f32x4{0.f, 0.f, 0.f, 0.f};
  lsacc[1] = f32x4{0.f, 0.f, 0.f, 0.f};

  // bf16 ones vector for the denominator MFMA
  u32x4 onesw;
  onesw[0] = 0x3F803F80u; onesw[1] = 0x3F803F80u;
  onesw[2] = 0x3F803F80u; onesw[3] = 0x3F803F80u;
  bf16x8 onesf; __builtin_memcpy(&onesf, &onesw, 16);

  GLL(kp + kgl0, &Ks[0][(wave * 8) * 64]);
  GLL(kp + kgl1, &Ks[0][(32 + wave * 8) * 64]);
  GLL(vp + vgl0, &Vs[0][(wave * 8) * 64]);
  GLL(vp + vgl1, &Vs[0][(32 + wave * 8) * 64]);

#pragma unroll 2
  for (int kt = 0; kt < 32; ++kt) {
    __syncthreads();
    const u16* KsB = Ks[kt & 1];
    const u16* VsB = Vs[kt & 1];
    if (kt + 1 < 32) {
      u16* KsN = (u16*)Ks[(kt & 1) ^ 1];
      u16* VsN = (u16*)Vs[(kt & 1) ^ 1];
      const u16* kpn = kp + (size_t)(kt + 1) * 32768;
      const u16* vpn = vp + (size_t)(kt + 1) * 64;
      GLL(kpn + kgl0, KsN + (wave * 8) * 64);
      GLL(kpn + kgl1, KsN + (32 + wave * 8) * 64);
      GLL(vpn + vgl0, VsN + (wave * 8) * 64);
      GLL(vpn + vgl1, VsN + (32 + wave * 8) * 64);
    }

    // ---- K fragments, then all QK MFMAs back-to-back ----
    bf16x8 kf[2][2];
#pragma unroll
    for (int t = 0; t < 2; ++t) {
      kf[t][0] = ld8(KsB + kb[t][0]);
      kf[t][1] = ld8(KsB + kb[t][1]);
    }
    f32x4 sa[2][2];
    __builtin_amdgcn_s_setprio(1);
#pragma unroll
    for (int t = 0; t < 2; ++t)
#pragma unroll
      for (int qt = 0; qt < 2; ++qt) {
        f32x4 z = f32x4{0.f, 0.f, 0.f, 0.f};
        z = __builtin_amdgcn_mfma_f32_16x16x32_bf16(kf[t][0], aq[qt][0], z, 0, 0, 0);
        z = __builtin_amdgcn_mfma_f32_16x16x32_bf16(kf[t][1], aq[qt][1], z, 0, 0, 0);
        sa[t][qt] = z;
      }
    __builtin_amdgcn_s_setprio(0);

    // ---- exp + pack into P fragments (j=0..3 <- t=0, j=4..7 <- t=1) ----
    u32x4 pw[2];
#pragma unroll
    for (int t = 0; t < 2; ++t)
#pragma unroll
      for (int qt = 0; qt < 2; ++qt) {
        float p0 = __builtin_amdgcn_exp2f(sa[t][qt][0]);
        float p1 = __builtin_amdgcn_exp2f(sa[t][qt][1]);
        float p2 = __builtin_amdgcn_exp2f(sa[t][qt][2]);
        float p3 = __builtin_amdgcn_exp2f(sa[t][qt][3]);
        pw[qt][t * 2]     = pkhi(p1, p0);
        pw[qt][t * 2 + 1] = pkhi(p3, p2);
      }
    bf16x8 pf[2];
    __builtin_memcpy(&pf[0], &pw[0], 16);
    __builtin_memcpy(&pf[1], &pw[1], 16);

    // ---- PV + denominator MFMAs ----
    __builtin_amdgcn_s_setprio(1);
#pragma unroll
    for (int dt = 0; dt < 4; ++dt) {
      u32x2 lo = *(const u32x2*)(VsB + vblo + dt * 1024);
      u32x2 hi = *(const u32x2*)(VsB + vbhi + dt * 1024);
      u32x4 w;
      w[0] = lo[0]; w[1] = lo[1]; w[2] = hi[0]; w[3] = hi[1];
      bf16x8 av; __builtin_memcpy(&av, &w, 16);
#pragma unroll
      for (int qt = 0; qt < 2; ++qt)
        oacc[dt][qt] = __builtin_amdgcn_mfma_f32_16x16x32_bf16(
            av, pf[qt], oacc[dt][qt], 0, 0, 0);
    }
#pragma unroll
    for (int qt = 0; qt < 2; ++qt)
      lsacc[qt] = __builtin_amdgcn_mfma_f32_16x16x32_bf16(
          onesf, pf[qt], lsacc[qt], 0, 0, 0);
    __builtin_amdgcn_s_setprio(0);
  }

  // lsacc[qt][g] = full sum over this wave's kv half for q-row qt*16+l16
  if (quad == 0) {
#pragma unroll
    for (int qt = 0; qt < 2; ++qt) Lr[wave][qt * 16 + l16] = lsacc[qt][0];
  }
  __syncthreads();

  float* R = (float*)&Ks[0][0];
  const int l7 = lane & 7;
  if (wave >= 2) {
    float* Rw = R + (wave - 2) * 2048;
#pragma unroll
    for (int dt = 0; dt < 4; ++dt)
#pragma unroll
      for (int qt = 0; qt < 2; ++qt) {
        int s = (dt * 2 + qt) ^ l7;
        *(f32x4*)&Rw[lane * 32 + s * 4] = oacc[dt][qt];
      }
  }
  __syncthreads();
  if (wave < 2) {
    float* Rw = R + wave * 2048;
    float inv[2];
#pragma unroll
    for (int qt = 0; qt < 2; ++qt)
      inv[qt] = 1.0f / (Lr[wave][qt * 16 + l16] + Lr[wave + 2][qt * 16 + l16]);
#pragma unroll
    for (int dt = 0; dt < 4; ++dt)
#pragma unroll
      for (int qt = 0; qt < 2; ++qt) {
        int s = (dt * 2 + qt) ^ l7;
        f32x4 v = *(f32x4*)&Rw[lane * 32 + s * 4];
        float i4 = inv[qt];
        float o0 = (oacc[dt][qt][0] + v[0]) * i4;
        float o1 = (oacc[dt][qt][1] + v[1]) * i4;
        float o2 = (oacc[dt][qt][2] + v[2]) * i4;
        float o3 = (oacc[dt][qt][3] + v[3]) * i4;
        u16* op = o + (size_t)(b * 2048 + qt0 + wave * 32 + qt * 16 + l16) * 512 +
                  h * 64 + dt * 16 + quad * 4;
        u32x2 pk;
        pk[0] = (unsigned)f2b(o0) | ((unsigned)f2b(o1) << 16);
        pk[1] = (unsigned)f2b(o2) | ((unsigned)f2b(o3) << 16);
        *(u32x2*)op = pk;
      }
  }
}

// ---------------------------------------------------------------------------
extern "C" void kernel_launch(void* const* d_in, const int* in_sizes, int n_in,
                              void* d_out, int out_size, void* d_ws,
                              size_t ws_size, hipStream_t stream) {
  const float* x   = (const float*)d_in[0];
  const float* Wq  = (const float*)d_in[1];
  const float* Wk  = (const float*)d_in[2];
  const float* Wv  = (const float*)d_in[3];
  const float* Wo  = (const float*)d_in[4];
  const float* bo  = (const float*)d_in[5];
  const float* g1  = (const float*)d_in[6];
  const float* bg1 = (const float*)d_in[7];
  const float* W1  = (const float*)d_in[8];
  const float* b1  = (const float*)d_in[9];
  const float* W2  = (const float*)d_in[10];
  const float* b2  = (const float*)d_in[11];
  const float* g2  = (const float*)d_in[12];
  const float* bg2 = (const float*)d_in[13];

  char* ws = (char*)d_ws;
  float* h    = (float*)ws;                        // 16 MB fp32 residual
  u16* yb     = (u16*)(ws + (16ll << 20));         // 8 MB LN output (bf16)
  u16* qb     = (u16*)(ws + (24ll << 20));         // 8 MB q / ffn-intermediate
  u16* kb     = (u16*)(ws + (32ll << 20));         // 8 MB k
  u16* vtb    = (u16*)(ws + (40ll << 20));         // 8 MB v transposed [b,h,d,n]
  u16* ob     = (u16*)(ws + (48ll << 20));         // 8 MB attn out
  u16* wtqkv  = (u16*)(ws + (56ll << 20));         // 6 MB [l][1536][512] bf16
  u16* wto    = (u16*)(ws + (62ll << 20));         // 2 MB
  u16* wt1    = (u16*)(ws + (64ll << 20));         // 2 MB
  u16* wt2    = (u16*)(ws + (66ll << 20));         // 2 MB  (total 68 MB)

  tr_all_k<<<dim3(16, 16, 24), dim3(32, 8), 0, stream>>>(
      Wq, Wk, Wv, Wo, W1, W2, wtqkv, wto, wt1, wt2);

  for (int l = 0; l < 4; ++l) {
    const float* hsrc = (l == 0) ? x : h;
    ln_k<<<2048, 256, 0, stream>>>(hsrc, g1 + l * 512, bg1 + l * 512, yb);
    gemm_qkv_k<<<dim3(128, 12), 512, 0, stream>>>(
        yb, wtqkv + l * 786432, qb, kb, vtb);
    attn_k<<<dim3(32, 32), 256, 0, stream>>>(qb, kb, vtb, ob);
    gemm2_k<EPI_RES><<<dim3(128, 4), 512, 0, stream>>>(
        ob, wto + l * 262144, bo + l * 512, nullptr, hsrc, h, nullptr);
    ln_k<<<2048, 256, 0, stream>>>(h, g2 + l * 512, bg2 + l * 512, yb);
    gemm2_k<EPI_GELU><<<dim3(128, 4), 512, 0, stream>>>(
        yb, wt1 + l * 262144, b1 + l * 512, qb, nullptr, nullptr, nullptr);
    gemm2_k<EPI_RES><<<dim3(128, 4), 512, 0, stream>>>(
        qb, wt2 + l * 262144, b2 + l * 512, nullptr, h, h,
        (l == 3) ? (float*)d_out : nullptr);
  }
}

// Round 8
// 517.579 us; speedup vs baseline: 1.1887x; 1.0553x over previous
//
#include <hip/hip_runtime.h>
#include <hip/hip_bf16.h>

// Problem: L=4 B=4 N=2048 D=512 H=8 HD=64. Inputs/outputs FP32.
// Weights transposed+cast to bf16 once; bf16 MFMA, fp32 accumulate; fp32
// residual stream. scale = 512^-0.5 (D**-0.5 per ref).
// Round 17: gemm2 -> 3-buffer counted-vmcnt pipeline (T3/T4), 72 KB LDS.
// Unlike attn-v8 (which lost occupancy 4->3 blocks/CU and regressed),
// gemm2 keeps exactly 2 blocks/CU (grid-limited) at 72 KB -> clean test:
//   wait vmcnt(3) [fill(kt) landed, fill(kt+1) in flight] -> s_barrier ->
//   issue fill(kt+2) -> compute. No vmcnt(0) drain in the main loop.
// Full 8-round unroll => all buffer indices compile-time. qkv (BK=64 dbuf)
// and attn v7 unchanged from round 16 (546us).

typedef __bf16 bf16x8 __attribute__((ext_vector_type(8)));
typedef float f32x4 __attribute__((ext_vector_type(4)));
typedef unsigned int u32x4 __attribute__((ext_vector_type(4)));
typedef unsigned int u32x2 __attribute__((ext_vector_type(2)));
typedef unsigned short u16;

__device__ __forceinline__ u16 f2b(float f) {  // RNE (values are finite)
  unsigned int u; __builtin_memcpy(&u, &f, 4);
  u += 0x7fffu + ((u >> 16) & 1u);
  return (u16)(u >> 16);
}
__device__ __forceinline__ bf16x8 ld8(const u16* p) {
  u32x4 t = *(const u32x4*)p;
  bf16x8 r; __builtin_memcpy(&r, &t, 16); return r;
}
__device__ __forceinline__ unsigned pkhi(float a, float b) {
  unsigned ua, ub; __builtin_memcpy(&ua, &a, 4); __builtin_memcpy(&ub, &b, 4);
  return __builtin_amdgcn_perm(ua, ub, 0x07060302u);
}

#define GLL(gp, lp) __builtin_amdgcn_global_load_lds( \
    (const __attribute__((address_space(1))) void*)(gp), \
    (__attribute__((address_space(3))) void*)(lp), 16, 0, 0)

__device__ __forceinline__ int swz(int r) { return (r + (r >> 2)) & 3; }

// ---------------------------------------------------------------------------
// All weight transposes in one launch. grid (16,16,24): z -> which(6) x l(4).
// out[l][n][k] = bf16(in[l][k][n]).
// ---------------------------------------------------------------------------
__global__ __launch_bounds__(256) void tr_all_k(
    const float* __restrict__ Wq, const float* __restrict__ Wk,
    const float* __restrict__ Wv, const float* __restrict__ Wo,
    const float* __restrict__ W1, const float* __restrict__ W2,
    u16* __restrict__ wtqkv, u16* __restrict__ wto,
    u16* __restrict__ wt1, u16* __restrict__ wt2) {
  __shared__ float t[32][33];
  int tx = threadIdx.x, ty = threadIdx.y;
  int z = blockIdx.z, which = z >> 2, l = z & 3;
  const float* in;
  u16* out;
  switch (which) {
    case 0: in = Wq; out = wtqkv + l * 786432; break;
    case 1: in = Wk; out = wtqkv + l * 786432 + 262144; break;
    case 2: in = Wv; out = wtqkv + l * 786432 + 524288; break;
    case 3: in = Wo; out = wto + l * 262144; break;
    case 4: in = W1; out = wt1 + l * 262144; break;
    default: in = W2; out = wt2 + l * 262144; break;
  }
  int k0 = blockIdx.y * 32, n0 = blockIdx.x * 32;
  const float* ip = in + l * 262144;
#pragma unroll
  for (int i = 0; i < 4; i++)
    t[ty + i * 8][tx] = ip[(k0 + ty + i * 8) * 512 + n0 + tx];
  __syncthreads();
#pragma unroll
  for (int i = 0; i < 4; i++)
    out[(n0 + ty + i * 8) * 512 + k0 + tx] = f2b(t[tx][ty + i * 8]);
}

// ---------------------------------------------------------------------------
// LayerNorm: one wave per token (D=512, 8 elems/lane), fp32 in, bf16 out
// ---------------------------------------------------------------------------
__global__ __launch_bounds__(256) void ln_k(const float* __restrict__ h,
                                            const float* __restrict__ gg,
                                            const float* __restrict__ bb,
                                            u16* __restrict__ y) {
  int tid = threadIdx.x, wave = tid >> 6, lane = tid & 63;
  int tok = blockIdx.x * 4 + wave;
  const float* hp = h + (size_t)tok * 512 + lane * 8;
  float x[8];
  *(float4*)&x[0] = *(const float4*)hp;
  *(float4*)&x[4] = *(const float4*)(hp + 4);
  float s = 0.f, ss = 0.f;
#pragma unroll
  for (int i = 0; i < 8; i++) { s += x[i]; ss += x[i] * x[i]; }
#pragma unroll
  for (int off = 1; off < 64; off <<= 1) {
    s += __shfl_xor(s, off, 64);
    ss += __shfl_xor(ss, off, 64);
  }
  float mean = s * (1.0f / 512.0f);
  float var = ss * (1.0f / 512.0f) - mean * mean;
  float rstd = rsqrtf(var + 1e-5f);
  u32x4 ov;
#pragma unroll
  for (int i = 0; i < 4; i++) {
    int d0 = lane * 8 + i * 2;
    float y0 = (x[i * 2]     - mean) * rstd * gg[d0]     + bb[d0];
    float y1 = (x[i * 2 + 1] - mean) * rstd * gg[d0 + 1] + bb[d0 + 1];
    ov[i] = (unsigned)f2b(y0) | ((unsigned)f2b(y1) << 16);
  }
  *(u32x4*)&y[(size_t)tok * 512 + lane * 8] = ov;
}

// ---------------------------------------------------------------------------
// GEMM2 v5: 64x128 tile, BK=64, 8 K-rounds, TRIPLE-buffered, 72 KB LDS,
// 512 threads (2x4 waves, wave-tile 32x32). grid (128 m, 4 n) -> 2/CU
// (same occupancy as dbuf: grid-limited). Counted vmcnt(3), raw s_barrier,
// fill(kt+2) issued after barrier. 8-chunk XOR swizzle. RES preloads hin.
// ---------------------------------------------------------------------------
enum { EPI_RES = 1, EPI_GELU = 2 };

template <int EPI>
__global__ __launch_bounds__(512, 4) void gemm2_k(
    const u16* __restrict__ A, const u16* __restrict__ Bt,
    const float* __restrict__ bias, u16* __restrict__ out0,
    const float* __restrict__ hin, float* __restrict__ hout,
    float* __restrict__ fout) {
  __shared__ __align__(16) u16 As[3][64 * 64];   // 3 x 8 KB
  __shared__ __align__(16) u16 Bs[3][128 * 64];  // 3 x 16 KB
  const int tid = threadIdx.x;
  const int wave = tid >> 6, lane = tid & 63;
  const int quad = lane >> 4, l16 = lane & 15;
  const int wm = wave >> 2, wn = wave & 3;
  const int m0 = blockIdx.x * 64;
  const int n0 = blockIdx.y * 128;
  const int mb = m0 + wm * 32, nb = n0 + wn * 32;

  // hin residual tile -> regs (RES only). Issued FIRST: vmcnt retires
  // in order, so these precede fill(0) and only add a one-time over-wait.
  float hr[2][2][4];
  if constexpr (EPI == EPI_RES) {
#pragma unroll
    for (int mi = 0; mi < 2; ++mi)
#pragma unroll
      for (int ni = 0; ni < 2; ++ni) {
        int r0 = mb + mi * 16 + quad * 4, c = nb + ni * 16 + l16;
#pragma unroll
        for (int g = 0; g < 4; ++g)
          hr[mi][ni][g] = hin[(size_t)(r0 + g) * 512 + c];
      }
  }

  f32x4 acc[2][2];
#pragma unroll
  for (int i = 0; i < 2; i++)
#pragma unroll
    for (int j = 0; j < 2; j++) acc[i][j] = f32x4{0.f, 0.f, 0.f, 0.f};

  // A: 64 rows x 8 chunks = 512 segs (1 GLL); B: 128 x 8 = 1024 (2 GLL)
  const int rowA = tid >> 3, cgA = (tid & 7) ^ (rowA & 7);
  const size_t agl = (size_t)(m0 + rowA) * 512 + cgA * 8;
  int rowB[2], cgB[2];
#pragma unroll
  for (int rnd = 0; rnd < 2; ++rnd) {
    int s = rnd * 512 + tid;
    rowB[rnd] = s >> 3;
    cgB[rnd] = (tid & 7) ^ (rowB[rnd] & 7);
  }
  const size_t bgl0 = (size_t)(n0 + rowB[0]) * 512 + cgB[0] * 8;
  const size_t bgl1 = (size_t)(n0 + rowB[1]) * 512 + cgB[1] * 8;

  // frag bases (kt-invariant): [mi/ni][ks]
  int kbA[2][2], kbB[2][2];
#pragma unroll
  for (int mi = 0; mi < 2; ++mi) {
    int r = wm * 32 + mi * 16 + l16;
#pragma unroll
    for (int ks = 0; ks < 2; ++ks)
      kbA[mi][ks] = r * 64 + ((ks * 4 + quad) ^ (r & 7)) * 8;
  }
#pragma unroll
  for (int ni = 0; ni < 2; ++ni) {
    int r = wn * 32 + ni * 16 + l16;
#pragma unroll
    for (int ks = 0; ks < 2; ++ks)
      kbB[ni][ks] = r * 64 + ((ks * 4 + quad) ^ (r & 7)) * 8;
  }

  // prologue: fill buffers 0 (kt=0) and 1 (kt=1)
  GLL(A + agl, &As[0][(wave * 64) * 8]);
  GLL(Bt + bgl0, &Bs[0][(wave * 64) * 8]);
  GLL(Bt + bgl1, &Bs[0][(512 + wave * 64) * 8]);
  GLL(A + agl + 64, &As[1][(wave * 64) * 8]);
  GLL(Bt + bgl0 + 64, &Bs[1][(wave * 64) * 8]);
  GLL(Bt + bgl1 + 64, &Bs[1][(512 + wave * 64) * 8]);

#pragma unroll
  for (int kt = 0; kt < 8; ++kt) {
    // fill(kt) landed; fill(kt+1)'s 3 loads may stay in flight
    if (kt < 7) {
      asm volatile("s_waitcnt vmcnt(3)" ::: "memory");
    } else {
      asm volatile("s_waitcnt vmcnt(0)" ::: "memory");
    }
    __builtin_amdgcn_sched_barrier(0);
    __builtin_amdgcn_s_barrier();
    __builtin_amdgcn_sched_barrier(0);

    const u16* AsB = As[kt % 3];
    const u16* BsB = Bs[kt % 3];
    if (kt + 2 < 8) {
      u16* AsN = (u16*)As[(kt + 2) % 3];
      u16* BsN = (u16*)Bs[(kt + 2) % 3];
      const int k2 = (kt + 2) * 64;
      GLL(A + agl + k2, AsN + (wave * 64) * 8);
      GLL(Bt + bgl0 + k2, BsN + (wave * 64) * 8);
      GLL(Bt + bgl1 + k2, BsN + (512 + wave * 64) * 8);
    }

#pragma unroll
    for (int ks = 0; ks < 2; ++ks) {
      bf16x8 af[2], bf_[2];
#pragma unroll
      for (int mi = 0; mi < 2; ++mi) af[mi] = ld8(AsB + kbA[mi][ks]);
#pragma unroll
      for (int ni = 0; ni < 2; ++ni) bf_[ni] = ld8(BsB + kbB[ni][ks]);
#pragma unroll
      for (int mi = 0; mi < 2; ++mi)
#pragma unroll
        for (int ni = 0; ni < 2; ++ni)
          acc[mi][ni] = __builtin_amdgcn_mfma_f32_16x16x32_bf16(
              af[mi], bf_[ni], acc[mi][ni], 0, 0, 0);
    }
  }

  // Epilogue. C layout: row = quad*4+reg, col = l16.
#pragma unroll
  for (int mi = 0; mi < 2; ++mi) {
#pragma unroll
    for (int ni = 0; ni < 2; ++ni) {
      f32x4 a = acc[mi][ni];
      int r0 = mb + mi * 16 + quad * 4;
      int c = nb + ni * 16 + l16;
      float bi = bias[c];
      if constexpr (EPI == EPI_RES) {
#pragma unroll
        for (int g = 0; g < 4; ++g) {
          float v = hr[mi][ni][g] + a[g] + bi;
          hout[(size_t)(r0 + g) * 512 + c] = v;
          if (fout) fout[(size_t)(r0 + g) * 512 + c] = v;
        }
      } else {  // GELU
#pragma unroll
        for (int g = 0; g < 4; ++g) {
          float t = a[g] + bi;
          float gl = 0.5f * t * (1.0f + erff(t * 0.70710678118654752f));
          out0[(size_t)(r0 + g) * 512 + c] = f2b(gl);
        }
      }
    }
  }
}

// ---------------------------------------------------------------------------
// QKV GEMM v3: 64x128 tile, BK=64, 8 K-rounds, dbuf, 48 KB LDS, 512 thr.
// grid (128 m, 12 n). Epilogue splits Q (pre-scaled), K, V^T.
// ---------------------------------------------------------------------------
__global__ __launch_bounds__(512, 6) void gemm_qkv_k(
    const u16* __restrict__ A, const u16* __restrict__ Bt,
    u16* __restrict__ outq, u16* __restrict__ outk, u16* __restrict__ outvt) {
  __shared__ __align__(16) u16 As[2][64 * 64];   // 2 x 8 KB
  __shared__ __align__(16) u16 Bs[2][128 * 64];  // 2 x 16 KB
  const int tid = threadIdx.x;
  const int wave = tid >> 6, lane = tid & 63;
  const int quad = lane >> 4, l16 = lane & 15;
  const int wm = wave >> 2, wn = wave & 3;
  const int m0 = blockIdx.x * 64;
  const int n0 = blockIdx.y * 128;
  const int mb = m0 + wm * 32, nb = n0 + wn * 32;

  f32x4 acc[2][2];
#pragma unroll
  for (int i = 0; i < 2; i++)
#pragma unroll
    for (int j = 0; j < 2; j++) acc[i][j] = f32x4{0.f, 0.f, 0.f, 0.f};

  const int rowA = tid >> 3, cgA = (tid & 7) ^ (rowA & 7);
  const size_t agl = (size_t)(m0 + rowA) * 512 + cgA * 8;
  int rowB[2], cgB[2];
#pragma unroll
  for (int rnd = 0; rnd < 2; ++rnd) {
    int s = rnd * 512 + tid;
    rowB[rnd] = s >> 3;
    cgB[rnd] = (tid & 7) ^ (rowB[rnd] & 7);
  }
  const size_t bgl0 = (size_t)(n0 + rowB[0]) * 512 + cgB[0] * 8;
  const size_t bgl1 = (size_t)(n0 + rowB[1]) * 512 + cgB[1] * 8;

  int kbA[2][2], kbB[2][2];
#pragma unroll
  for (int mi = 0; mi < 2; ++mi) {
    int r = wm * 32 + mi * 16 + l16;
#pragma unroll
    for (int ks = 0; ks < 2; ++ks)
      kbA[mi][ks] = r * 64 + ((ks * 4 + quad) ^ (r & 7)) * 8;
  }
#pragma unroll
  for (int ni = 0; ni < 2; ++ni) {
    int r = wn * 32 + ni * 16 + l16;
#pragma unroll
    for (int ks = 0; ks < 2; ++ks)
      kbB[ni][ks] = r * 64 + ((ks * 4 + quad) ^ (r & 7)) * 8;
  }

  // prologue: stage kt=0 into buf 0
  GLL(A + agl, &As[0][(wave * 64) * 8]);
  GLL(Bt + bgl0, &Bs[0][(wave * 64) * 8]);
  GLL(Bt + bgl1, &Bs[0][(512 + wave * 64) * 8]);

#pragma unroll 2
  for (int kt = 0; kt < 8; ++kt) {
    __syncthreads();
    const u16* AsB = As[kt & 1];
    const u16* BsB = Bs[kt & 1];
    if (kt + 1 < 8) {
      u16* AsN = (u16*)As[(kt & 1) ^ 1];
      u16* BsN = (u16*)Bs[(kt & 1) ^ 1];
      const int k1 = (kt + 1) * 64;
      GLL(A + agl + k1, AsN + (wave * 64) * 8);
      GLL(Bt + bgl0 + k1, BsN + (wave * 64) * 8);
      GLL(Bt + bgl1 + k1, BsN + (512 + wave * 64) * 8);
    }

#pragma unroll
    for (int ks = 0; ks < 2; ++ks) {
      bf16x8 af[2], bf_[2];
#pragma unroll
      for (int mi = 0; mi < 2; ++mi) af[mi] = ld8(AsB + kbA[mi][ks]);
#pragma unroll
      for (int ni = 0; ni < 2; ++ni) bf_[ni] = ld8(BsB + kbB[ni][ks]);
#pragma unroll
      for (int mi = 0; mi < 2; ++mi)
#pragma unroll
        for (int ni = 0; ni < 2; ++ni)
          acc[mi][ni] = __builtin_amdgcn_mfma_f32_16x16x32_bf16(
              af[mi], bf_[ni], acc[mi][ni], 0, 0, 0);
    }
  }

  // Epilogue: split Q/K/V^T
#pragma unroll
  for (int mi = 0; mi < 2; ++mi) {
#pragma unroll
    for (int ni = 0; ni < 2; ++ni) {
      f32x4 a = acc[mi][ni];
      int r0 = mb + mi * 16 + quad * 4;
      int c = nb + ni * 16 + l16;
      if (c < 512) {
        const float C2 = 0.06375871506958306f;  // 512^-0.5 * log2(e)
#pragma unroll
        for (int g = 0; g < 4; ++g) outq[(size_t)(r0 + g) * 512 + c] = f2b(a[g] * C2);
      } else if (c < 1024) {
#pragma unroll
        for (int g = 0; g < 4; ++g) outk[(size_t)(r0 + g) * 512 + (c - 512)] = f2b(a[g]);
      } else {
        int cv = c - 1024, hh = cv >> 6, dd = cv & 63;
        int bb = r0 >> 11, nt = r0 & 2047;
        u32x2 pk;
        pk[0] = (unsigned)f2b(a[0]) | ((unsigned)f2b(a[1]) << 16);
        pk[1] = (unsigned)f2b(a[2]) | ((unsigned)f2b(a[3]) << 16);
        *(u32x2*)&outvt[((size_t)(bb * 8 + hh) * 64 + dd) * 2048 + nt] = pk;
      }
    }
  }
}

// ---------------------------------------------------------------------------
// Flash attention v7 (2x2 split). grid (32 bh, 32 qt) -> XCD = bh%8.
// PV uses full-rate 16x16x32 MFMA with k<->kv mapping
//   k = quad*8 + t*4 + g  <->  kv = kvs*32 + t*16 + quad*4 + g
// (a) softmax denominator via ones-MFMA (l = ones x P); (b) all 8 QK MFMAs
// issue before the exp phase.
// ---------------------------------------------------------------------------
__global__ __launch_bounds__(256, 4) void attn_k(const u16* __restrict__ q,
                                                 const u16* __restrict__ k,
                                                 const u16* __restrict__ vt,
                                                 u16* __restrict__ o) {
  __shared__ __align__(16) u16 Ks[2][64 * 64];   // 16 KB
  __shared__ __align__(16) u16 Vs[2][64 * 64];   // 16 KB
  __shared__ float Lr[4][32];                    // 512 B
  const int tid = threadIdx.x, wave = tid >> 6, lane = tid & 63;
  const int quad = lane >> 4, l16 = lane & 15;
  const int swl = l16 & 7;
  const int qh2 = wave & 1, kvs = wave >> 1;
  const int bh = blockIdx.x, b = bh >> 3, h = bh & 7;
  const int qt0 = blockIdx.y * 64;

  const u16* qpb = q + (size_t)(b * 2048 + qt0 + qh2 * 32) * 512 + h * 64;
  bf16x8 aq[2][2];
#pragma unroll
  for (int qt = 0; qt < 2; ++qt) {
    const u16* qp = qpb + (size_t)(qt * 16 + l16) * 512;
    aq[qt][0] = ld8(qp + quad * 8);
    aq[qt][1] = ld8(qp + 32 + quad * 8);
  }

  const u16* kp = k + (size_t)b * 2048 * 512 + h * 64;
  const u16* vp = vt + (size_t)bh * 64 * 2048;

  const int srow = lane >> 3, schk = lane & 7, sgc = schk ^ srow;
  const int krow0 = wave * 8 + srow;
  const size_t kgl0 = (size_t)krow0 * 512 + sgc * 8;
  const size_t kgl1 = (size_t)(krow0 + 32) * 512 + sgc * 8;
  const size_t vgl0 = (size_t)krow0 * 2048 + sgc * 8;
  const size_t vgl1 = (size_t)(krow0 + 32) * 2048 + sgc * 8;

  int kb[2][2];
#pragma unroll
  for (int t = 0; t < 2; ++t) {
    kb[t][0] = (kvs * 32 + t * 16 + l16) * 64 + ((quad)     ^ swl) * 8;
    kb[t][1] = (kvs * 32 + t * 16 + l16) * 64 + ((4 + quad) ^ swl) * 8;
  }
  // V^T fragment bases: row l16 (+dt*16), col chunks (kv units of 8):
  const int vblo = l16 * 64 + (((kvs << 2) + (quad >> 1)) ^ swl) * 8 + (quad & 1) * 4;
  const int vbhi = l16 * 64 + (((kvs << 2) + 2 + (quad >> 1)) ^ swl) * 8 + (quad & 1) * 4;

  f32x4 oacc[4][2];
#pragma unroll
  for (int i = 0; i < 4; i++)
#pragma unroll
    for (int j = 0; j < 2; j++) oacc[i][j] = f32x4{0.f, 0.f, 0.f, 0.f};
  f32x4 lsacc[2];
  lsacc[0] = f32x4{0.f, 0.f, 0.f, 0.f};
  lsacc[1] = f32x4{0.f, 0.f, 0.f, 0.f};

  // bf16 ones vector for the denominator MFMA
  u32x4 onesw;
  onesw[0] = 0x3F803F80u; onesw[1] = 0x3F803F80u;
  onesw[2] = 0x3F803F80u; onesw[3] = 0x3F803F80u;
  bf16x8 onesf; __builtin_memcpy(&onesf, &onesw, 16);

  GLL(kp + kgl0, &Ks[0][(wave * 8) * 64]);
  GLL(kp + kgl1, &Ks[0][(32 + wave * 8) * 64]);
  GLL(vp + vgl0, &Vs[0][(wave * 8) * 64]);
  GLL(vp + vgl1, &Vs[0][(32 + wave * 8) * 64]);

#pragma unroll 2
  for (int kt = 0; kt < 32; ++kt) {
    __syncthreads();
    const u16* KsB = Ks[kt & 1];
    const u16* VsB = Vs[kt & 1];
    if (kt + 1 < 32) {
      u16* KsN = (u16*)Ks[(kt & 1) ^ 1];
      u16* VsN = (u16*)Vs[(kt & 1) ^ 1];
      const u16* kpn = kp + (size_t)(kt + 1) * 32768;
      const u16* vpn = vp + (size_t)(kt + 1) * 64;
      GLL(kpn + kgl0, KsN + (wave * 8) * 64);
      GLL(kpn + kgl1, KsN + (32 + wave * 8) * 64);
      GLL(vpn + vgl0, VsN + (wave * 8) * 64);
      GLL(vpn + vgl1, VsN + (32 + wave * 8) * 64);
    }

    // ---- K fragments, then all QK MFMAs back-to-back ----
    bf16x8 kf[2][2];
#pragma unroll
    for (int t = 0; t < 2; ++t) {
      kf[t][0] = ld8(KsB + kb[t][0]);
      kf[t][1] = ld8(KsB + kb[t][1]);
    }
    f32x4 sa[2][2];
    __builtin_amdgcn_s_setprio(1);
#pragma unroll
    for (int t = 0; t < 2; ++t)
#pragma unroll
      for (int qt = 0; qt < 2; ++qt) {
        f32x4 z = f32x4{0.f, 0.f, 0.f, 0.f};
        z = __builtin_amdgcn_mfma_f32_16x16x32_bf16(kf[t][0], aq[qt][0], z, 0, 0, 0);
        z = __builtin_amdgcn_mfma_f32_16x16x32_bf16(kf[t][1], aq[qt][1], z, 0, 0, 0);
        sa[t][qt] = z;
      }
    __builtin_amdgcn_s_setprio(0);

    // ---- exp + pack into P fragments (j=0..3 <- t=0, j=4..7 <- t=1) ----
    u32x4 pw[2];
#pragma unroll
    for (int t = 0; t < 2; ++t)
#pragma unroll
      for (int qt = 0; qt < 2; ++qt) {
        float p0 = __builtin_amdgcn_exp2f(sa[t][qt][0]);
        float p1 = __builtin_amdgcn_exp2f(sa[t][qt][1]);
        float p2 = __builtin_amdgcn_exp2f(sa[t][qt][2]);
        float p3 = __builtin_amdgcn_exp2f(sa[t][qt][3]);
        pw[qt][t * 2]     = pkhi(p1, p0);
        pw[qt][t * 2 + 1] = pkhi(p3, p2);
      }
    bf16x8 pf[2];
    __builtin_memcpy(&pf[0], &pw[0], 16);
    __builtin_memcpy(&pf[1], &pw[1], 16);

    // ---- PV + denominator MFMAs ----
    __builtin_amdgcn_s_setprio(1);
#pragma unroll
    for (int dt = 0; dt < 4; ++dt) {
      u32x2 lo = *(const u32x2*)(VsB + vblo + dt * 1024);
      u32x2 hi = *(const u32x2*)(VsB + vbhi + dt * 1024);
      u32x4 w;
      w[0] = lo[0]; w[1] = lo[1]; w[2] = hi[0]; w[3] = hi[1];
      bf16x8 av; __builtin_memcpy(&av, &w, 16);
#pragma unroll
      for (int qt = 0; qt < 2; ++qt)
        oacc[dt][qt] = __builtin_amdgcn_mfma_f32_16x16x32_bf16(
            av, pf[qt], oacc[dt][qt], 0, 0, 0);
    }
#pragma unroll
    for (int qt = 0; qt < 2; ++qt)
      lsacc[qt] = __builtin_amdgcn_mfma_f32_16x16x32_bf16(
          onesf, pf[qt], lsacc[qt], 0, 0, 0);
    __builtin_amdgcn_s_setprio(0);
  }

  // lsacc[qt][g] = full sum over this wave's kv half for q-row qt*16+l16
  if (quad == 0) {
#pragma unroll
    for (int qt = 0; qt < 2; ++qt) Lr[wave][qt * 16 + l16] = lsacc[qt][0];
  }
  __syncthreads();

  float* R = (float*)&Ks[0][0];
  const int l7 = lane & 7;
  if (wave >= 2) {
    float* Rw = R + (wave - 2) * 2048;
#pragma unroll
    for (int dt = 0; dt < 4; ++dt)
#pragma unroll
      for (int qt = 0; qt < 2; ++qt) {
        int s = (dt * 2 + qt) ^ l7;
        *(f32x4*)&Rw[lane * 32 + s * 4] = oacc[dt][qt];
      }
  }
  __syncthreads();
  if (wave < 2) {
    float* Rw = R + wave * 2048;
    float inv[2];
#pragma unroll
    for (int qt = 0; qt < 2; ++qt)
      inv[qt] = 1.0f / (Lr[wave][qt * 16 + l16] + Lr[wave + 2][qt * 16 + l16]);
#pragma unroll
    for (int dt = 0; dt < 4; ++dt)
#pragma unroll
      for (int qt = 0; qt < 2; ++qt) {
        int s = (dt * 2 + qt) ^ l7;
        f32x4 v = *(f32x4*)&Rw[lane * 32 + s * 4];
        float i4 = inv[qt];
        float o0 = (oacc[dt][qt][0] + v[0]) * i4;
        float o1 = (oacc[dt][qt][1] + v[1]) * i4;
        float o2 = (oacc[dt][qt][2] + v[2]) * i4;
        float o3 = (oacc[dt][qt][3] + v[3]) * i4;
        u16* op = o + (size_t)(b * 2048 + qt0 + wave * 32 + qt * 16 + l16) * 512 +
                  h * 64 + dt * 16 + quad * 4;
        u32x2 pk;
        pk[0] = (unsigned)f2b(o0) | ((unsigned)f2b(o1) << 16);
        pk[1] = (unsigned)f2b(o2) | ((unsigned)f2b(o3) << 16);
        *(u32x2*)op = pk;
      }
  }
}

// ---------------------------------------------------------------------------
extern "C" void kernel_launch(void* const* d_in, const int* in_sizes, int n_in,
                              void* d_out, int out_size, void* d_ws,
                              size_t ws_size, hipStream_t stream) {
  const float* x   = (const float*)d_in[0];
  const float* Wq  = (const float*)d_in[1];
  const float* Wk  = (const float*)d_in[2];
  const float* Wv  = (const float*)d_in[3];
  const float* Wo  = (const float*)d_in[4];
  const float* bo  = (const float*)d_in[5];
  const float* g1  = (const float*)d_in[6];
  const float* bg1 = (const float*)d_in[7];
  const float* W1  = (const float*)d_in[8];
  const float* b1  = (const float*)d_in[9];
  const float* W2  = (const float*)d_in[10];
  const float* b2  = (const float*)d_in[11];
  const float* g2  = (const float*)d_in[12];
  const float* bg2 = (const float*)d_in[13];

  char* ws = (char*)d_ws;
  float* h    = (float*)ws;                        // 16 MB fp32 residual
  u16* yb     = (u16*)(ws + (16ll << 20));         // 8 MB LN output (bf16)
  u16* qb     = (u16*)(ws + (24ll << 20));         // 8 MB q / ffn-intermediate
  u16* kb     = (u16*)(ws + (32ll << 20));         // 8 MB k
  u16* vtb    = (u16*)(ws + (40ll << 20));         // 8 MB v transposed [b,h,d,n]
  u16* ob     = (u16*)(ws + (48ll << 20));         // 8 MB attn out
  u16* wtqkv  = (u16*)(ws + (56ll << 20));         // 6 MB [l][1536][512] bf16
  u16* wto    = (u16*)(ws + (62ll << 20));         // 2 MB
  u16* wt1    = (u16*)(ws + (64ll << 20));         // 2 MB
  u16* wt2    = (u16*)(ws + (66ll << 20));         // 2 MB  (total 68 MB)

  tr_all_k<<<dim3(16, 16, 24), dim3(32, 8), 0, stream>>>(
      Wq, Wk, Wv, Wo, W1, W2, wtqkv, wto, wt1, wt2);

  for (int l = 0; l < 4; ++l) {
    const float* hsrc = (l == 0) ? x : h;
    ln_k<<<2048, 256, 0, stream>>>(hsrc, g1 + l * 512, bg1 + l * 512, yb);
    gemm_qkv_k<<<dim3(128, 12), 512, 0, stream>>>(
        yb, wtqkv + l * 786432, qb, kb, vtb);
    attn_k<<<dim3(32, 32), 256, 0, stream>>>(qb, kb, vtb, ob);
    gemm2_k<EPI_RES><<<dim3(128, 4), 512, 0, stream>>>(
        ob, wto + l * 262144, bo + l * 512, nullptr, hsrc, h, nullptr);
    ln_k<<<2048, 256, 0, stream>>>(h, g2 + l * 512, bg2 + l * 512, yb);
    gemm2_k<EPI_GELU><<<dim3(128, 4), 512, 0, stream>>>(
        yb, wt1 + l * 262144, b1 + l * 512, qb, nullptr, nullptr, nullptr);
    gemm2_k<EPI_RES><<<dim3(128, 4), 512, 0, stream>>>(
        qb, wt2 + l * 262144, b2 + l * 512, nullptr, h, h,
        (l == 3) ? (float*)d_out : nullptr);
  }
}